// Round 2
// baseline (855.975 us; speedup 1.0000x reference)
//
#include <hip/hip_runtime.h>
#include <hip/hip_cooperative_groups.h>
#include <stdint.h>

namespace cg = cooperative_groups;

#define NNODES 8192
#define KP1 4096
#define KP2 2048
#define FIN 16
#define FH 32
#define COUT 2
#define STRA 320   // max off-diag nnz/row; mean ~163, sigma ~12.6 -> >12 sigma headroom
#define STRS 320
#define CGRID_MAX 1024

typedef unsigned short u16;
typedef unsigned int u32;

// ---------------------------------------------------------------------------
// Kernel 1: blocks [0,n) stream the 256MB dense adjacency ONCE (float4,
// coalesced, block-local LDS counting) -> u16 ELL; blocks [n,...) compute
// Z1 = x @ W1 (independent co-launched work).
// ---------------------------------------------------------------------------
__global__ __launch_bounds__(256) void build_ell(const float* __restrict__ A, int n, int stride,
        u16* __restrict__ ell, int* __restrict__ rowcnt, int* __restrict__ diag, float* __restrict__ dnorm,
        const float* __restrict__ Xf, const float* __restrict__ Wf, float* __restrict__ Zf, int kf)
{
    if ((int)blockIdx.x >= n) {
        int t = ((int)blockIdx.x - n) * 256 + threadIdx.x;
        int i = t >> 5;
        int f = t & 31;
        const float* xr = Xf + (size_t)i * kf;
        float acc = 0.0f;
        for (int k = 0; k < kf; ++k) acc += xr[k] * Wf[k * 32 + f];
        Zf[t] = acc;
        return;
    }
    __shared__ int cnt;
    __shared__ int dg;
    int row = blockIdx.x;
    if (threadIdx.x == 0) { cnt = 0; dg = 0; }
    __syncthreads();
    const float4* arow4 = (const float4*)(A + (size_t)row * n);
    u16* erow = ell + (size_t)row * stride;
    int n4 = n >> 2;
    for (int c4 = threadIdx.x; c4 < n4; c4 += 256) {
        float4 v = arow4[c4];
        if (v.x == 0.0f && v.y == 0.0f && v.z == 0.0f && v.w == 0.0f) continue;
        int cb = c4 << 2;
        if (v.x != 0.0f) {
            if (cb == row) dg = 1;
            else { int p = atomicAdd(&cnt, 1); if (p < stride) erow[p] = (u16)cb; }
        }
        if (v.y != 0.0f) {
            int c = cb + 1;
            if (c == row) dg = 1;
            else { int p = atomicAdd(&cnt, 1); if (p < stride) erow[p] = (u16)c; }
        }
        if (v.z != 0.0f) {
            int c = cb + 2;
            if (c == row) dg = 1;
            else { int p = atomicAdd(&cnt, 1); if (p < stride) erow[p] = (u16)c; }
        }
        if (v.w != 0.0f) {
            int c = cb + 3;
            if (c == row) dg = 1;
            else { int p = atomicAdd(&cnt, 1); if (p < stride) erow[p] = (u16)c; }
        }
    }
    __syncthreads();
    if (threadIdx.x == 0) {
        int cf = cnt;
        rowcnt[row] = cf < stride ? cf : stride;
        diag[row] = dg;
        dnorm[row] = rsqrtf((float)(cf + dg + 1) + 1e-10f);
    }
}

// ---------------------------------------------------------------------------
// Shared phase bodies (used by the cooperative pipeline AND the fallback path)
// ---------------------------------------------------------------------------
struct TkS {
    u32 hist[4][256];
    u32 wsum[4];
    u32 pref;
    u32 rem;
};  // 4,120 B — LDS no longer limits occupancy

__device__ __forceinline__ u32 km_of(float f)
{
    u32 u = __float_as_uint(f);
    u32 m;
    if (u & 0x80000000u) m = ~u; else m = u | 0x80000000u;  // monotone asc in float
    return ~m;                                              // asc in km == desc in score
}

// Exact top-K (jax.lax.top_k set semantics: value desc, index-asc ties).
// Block-local: call from exactly one block (256 threads). Keys recomputed from
// scores each pass (L1-resident, 32KB max) instead of a 32KB LDS cache.
__device__ void topk_block0(TkS& s, const float* __restrict__ scores, int n, int K,
                            int* __restrict__ rank, int* __restrict__ idxlist, int tid)
{
    int wv = tid >> 6;
    int lane = tid & 63;
    int per = n >> 8;       // 32 (n=8192) or 16 (n=4096)
    int base = tid * per;
    if (tid == 0) { s.pref = 0u; s.rem = (u32)K; }
    __syncthreads();
    for (int bp = 3; bp >= 0; --bp) {
        s.hist[0][tid] = 0u;
        s.hist[1][tid] = 0u;
        s.hist[2][tid] = 0u;
        s.hist[3][tid] = 0u;
        __syncthreads();                 // hist zeroed; prev-iter pref visible
        u32 maskhi = 0u;
        if (bp < 3) maskhi = 0xFFFFFFFFu << ((bp + 1) * 8);
        u32 pref = s.pref;
        u32 rem = s.rem;
        for (int e = 0; e < per; ++e) {
            u32 km = km_of(scores[base + e]);
            if ((km & maskhi) == pref) atomicAdd(&s.hist[wv][(km >> (bp * 8)) & 255u], 1u);
        }
        __syncthreads();                 // atomics done
        u32 tot = s.hist[0][tid] + s.hist[1][tid] + s.hist[2][tid] + s.hist[3][tid];
        u32 vv = tot;
        u32 t2;
        t2 = __shfl(vv, lane - 1);  if (lane >= 1)  vv += t2;
        t2 = __shfl(vv, lane - 2);  if (lane >= 2)  vv += t2;
        t2 = __shfl(vv, lane - 4);  if (lane >= 4)  vv += t2;
        t2 = __shfl(vv, lane - 8);  if (lane >= 8)  vv += t2;
        t2 = __shfl(vv, lane - 16); if (lane >= 16) vv += t2;
        t2 = __shfl(vv, lane - 32); if (lane >= 32) vv += t2;
        if (lane == 63) s.wsum[wv] = vv;
        __syncthreads();                 // wave sums visible
        u32 add = 0u;
        if (wv > 0) add += s.wsum[0];
        if (wv > 1) add += s.wsum[1];
        if (wv > 2) add += s.wsum[2];
        u32 cum = vv + add;
        if (tot != 0u && cum >= rem && cum - tot < rem) {  // unique boundary bin
            s.pref = pref | ((u32)tid << (bp * 8));
            s.rem = rem - (cum - tot);
        }
    }
    __syncthreads();
    u32 T = s.pref;        // K-th smallest km
    u32 need_eq = s.rem;   // how many km==T to take (lowest node index first)
    u32 run = 0u;          // high16 = #(km<T), low16 = #(km==T)
    for (int e = 0; e < per; ++e) {
        u32 km = km_of(scores[base + e]);
        if (km < T) run += 0x10000u;
        else if (km == T) run += 1u;
    }
    u32 v2 = run;
    u32 t3;
    t3 = __shfl(v2, lane - 1);  if (lane >= 1)  v2 += t3;
    t3 = __shfl(v2, lane - 2);  if (lane >= 2)  v2 += t3;
    t3 = __shfl(v2, lane - 4);  if (lane >= 4)  v2 += t3;
    t3 = __shfl(v2, lane - 8);  if (lane >= 8)  v2 += t3;
    t3 = __shfl(v2, lane - 16); if (lane >= 16) v2 += t3;
    t3 = __shfl(v2, lane - 32); if (lane >= 32) v2 += t3;
    if (lane == 63) s.wsum[wv] = v2;
    __syncthreads();
    u32 add2 = 0u;
    if (wv > 0) add2 += s.wsum[0];
    if (wv > 1) add2 += s.wsum[1];
    if (wv > 2) add2 += s.wsum[2];
    u32 cur = v2 + add2 - run;   // exclusive prefix for this thread's chunk
    for (int e = 0; e < per; ++e) {
        int v = base + e;
        u32 km = km_of(scores[v]);
        u32 ltb = cur >> 16;
        u32 eqb = cur & 0xFFFFu;
        u32 eqs = eqb < need_eq ? eqb : need_eq;
        int sel = 0;
        if (km < T) { sel = 1; cur += 0x10000u; }
        else if (km == T) { if (eqb < need_eq) sel = 1; cur += 1u; }
        if (sel) {
            int r = (int)(ltb + eqs);
            rank[v] = r;
            idxlist[r] = v;
        } else {
            rank[v] = -1;
        }
    }
}

// Dense Zf = Xf @ Wf (fout=32), grid-stride over elements.
__device__ __forceinline__ void gemm32(const float* __restrict__ Xf, const float* __restrict__ Wf,
                                       float* __restrict__ Zf, int rows, int kf, int t0, int tstr)
{
    int tot = rows * 32;
    for (int t = t0; t < tot; t += tstr) {
        int i = t >> 5;
        int f = t & 31;
        const float* xr = Xf + (size_t)i * kf;
        float acc = 0.0f;
        for (int k = 0; k < kf; ++k) acc += xr[k] * Wf[k * 32 + f];
        Zf[t] = acc;
    }
}

// SpMM (F=32) + relu; one wave per row, 8 lanes per neighbor, float4 per lane.
template<bool REMAP, bool MASK, bool FW4, bool SC>
__device__ __forceinline__ void spmm_phase(
        const u16* __restrict__ ell, const int* __restrict__ rowcnt,
        const int* __restrict__ diag, const float* __restrict__ dnorm,
        const float* __restrict__ Z, const int* __restrict__ remap, const int* __restrict__ maskp,
        float* __restrict__ X, float* __restrict__ scores, const float* __restrict__ svec,
        const float* __restrict__ W4p, float* __restrict__ z4out,
        int n, int stride, int gwave, int nwaves, int lane)
{
    int g = lane >> 3;   // neighbor sub-slot 0..7
    int q = lane & 7;    // feature quad 0..7
    for (int wid = gwave; wid < n; wid += nwaves) {
        int cnt = rowcnt[wid];
        const u16* erow = ell + (size_t)wid * stride;
        float ax = 0.0f, ay = 0.0f, az = 0.0f, aw = 0.0f;
        for (int it = g; it < cnt; it += 8) {
            int c = erow[it];
            if (MASK && maskp[c] < 0) continue;
            int zc = REMAP ? remap[c] : c;
            float dn = dnorm[c];
            const float4* zp = (const float4*)(Z + (size_t)zc * 32);
            float4 zv = zp[q];
            ax += dn * zv.x;
            ay += dn * zv.y;
            az += dn * zv.z;
            aw += dn * zv.w;
        }
        ax += __shfl_xor(ax, 8);  ay += __shfl_xor(ay, 8);
        az += __shfl_xor(az, 8);  aw += __shfl_xor(aw, 8);
        ax += __shfl_xor(ax, 16); ay += __shfl_xor(ay, 16);
        az += __shfl_xor(az, 16); aw += __shfl_xor(aw, 16);
        ax += __shfl_xor(ax, 32); ay += __shfl_xor(ay, 32);
        az += __shfl_xor(az, 32); aw += __shfl_xor(aw, 32);
        if (g == 0) {   // lanes 0..7 hold the full sum for feature quad q
            float dr = dnorm[wid];
            bool selfok = !(MASK && maskp[wid] < 0);
            if (selfok) {
                int zc = REMAP ? remap[wid] : wid;
                const float4* zp = (const float4*)(Z + (size_t)zc * 32);
                float4 zv = zp[q];
                float cf = (float)(diag[wid] + 1) * dr;
                ax += cf * zv.x;
                ay += cf * zv.y;
                az += cf * zv.z;
                aw += cf * zv.w;
            }
            float ox = fmaxf(dr * ax, 0.0f);
            float oy = fmaxf(dr * ay, 0.0f);
            float oz = fmaxf(dr * az, 0.0f);
            float ow = fmaxf(dr * aw, 0.0f);
            if (FW4) {
                int kb = q * 4;
                float p0 = ox * W4p[(kb + 0) * 2 + 0] + oy * W4p[(kb + 1) * 2 + 0]
                         + oz * W4p[(kb + 2) * 2 + 0] + ow * W4p[(kb + 3) * 2 + 0];
                float p1 = ox * W4p[(kb + 0) * 2 + 1] + oy * W4p[(kb + 1) * 2 + 1]
                         + oz * W4p[(kb + 2) * 2 + 1] + ow * W4p[(kb + 3) * 2 + 1];
                p0 += __shfl_xor(p0, 1);
                p1 += __shfl_xor(p1, 1);
                p0 += __shfl_xor(p0, 2);
                p1 += __shfl_xor(p1, 2);
                p0 += __shfl_xor(p0, 4);
                p1 += __shfl_xor(p1, 4);
                if (q == 0) {
                    float2 r;
                    r.x = p0;
                    r.y = p1;
                    ((float2*)z4out)[wid] = r;
                }
            } else {
                float4 o;
                o.x = ox; o.y = oy; o.z = oz; o.w = ow;
                float4* xp = (float4*)(X + (size_t)wid * 32);
                xp[q] = o;
                if (SC) {
                    const float4* sp = (const float4*)svec;
                    float4 sv = sp[q];
                    float pp = o.x * sv.x + o.y * sv.y + o.z * sv.z + o.w * sv.w;
                    pp += __shfl_xor(pp, 1);
                    pp += __shfl_xor(pp, 2);
                    pp += __shfl_xor(pp, 4);
                    if (q == 0) scores[wid] = pp;
                }
            }
        }
    }
}

// Subgraph ELL for A1p = a[idx1][:,idx1]; wave-compaction via ballot.
__device__ __forceinline__ void subell_phase(const u16* __restrict__ ellA, const int* __restrict__ rowcntA,
        const int* __restrict__ diagA, const int* __restrict__ idx1, const int* __restrict__ rank1,
        u16* __restrict__ ellS, int* __restrict__ rowcntS, int* __restrict__ diagS, float* __restrict__ dnormS,
        int k1, int strideA, int strideS, int gwave, int nwaves, int lane)
{
    for (int wid = gwave; wid < k1; wid += nwaves) {
        int r = idx1[wid];
        int cnt = rowcntA[r];
        const u16* erow = ellA + (size_t)r * strideA;
        u16* srow = ellS + (size_t)wid * strideS;
        int outn = 0;
        for (int t0 = 0; t0 < cnt; t0 += 64) {
            int it = t0 + lane;
            int rk = -1;
            if (it < cnt) rk = rank1[erow[it]];
            unsigned long long b = __ballot(rk >= 0);
            int ofs = __popcll(b & ((1ull << lane) - 1ull));
            if (rk >= 0) srow[outn + ofs] = (u16)rk;
            outn += __popcll(b);
        }
        if (lane == 0) {
            int dg = diagA[r];
            rowcntS[wid] = outn;
            diagS[wid] = dg;
            dnormS[wid] = rsqrtf((float)(outn + dg + 1) + 1e-10f);
        }
    }
}

// Final SpMM (F=2) + 2-way softmax; unpool1 folded into the gat[] gather.
__device__ __forceinline__ void spmmout_phase(const u16* __restrict__ ell, const int* __restrict__ rowcnt,
        const int* __restrict__ diag, const float* __restrict__ dnorm, const float* __restrict__ Zr,
        const int* __restrict__ gat, float* __restrict__ out, int n, int stride,
        int gwave, int nwaves, int lane)
{
    const float2* Z2 = (const float2*)Zr;
    for (int wid = gwave; wid < n; wid += nwaves) {
        int cnt = rowcnt[wid];
        const u16* erow = ell + (size_t)wid * stride;
        float ax = 0.0f, ay = 0.0f;
        for (int it = lane; it < cnt; it += 64) {
            int c = erow[it];
            int rk = gat[c];
            if (rk >= 0) {
                float dn = dnorm[c];
                float2 zv = Z2[rk];
                ax += dn * zv.x;
                ay += dn * zv.y;
            }
        }
        ax += __shfl_xor(ax, 1);  ay += __shfl_xor(ay, 1);
        ax += __shfl_xor(ax, 2);  ay += __shfl_xor(ay, 2);
        ax += __shfl_xor(ax, 4);  ay += __shfl_xor(ay, 4);
        ax += __shfl_xor(ax, 8);  ay += __shfl_xor(ay, 8);
        ax += __shfl_xor(ax, 16); ay += __shfl_xor(ay, 16);
        ax += __shfl_xor(ax, 32); ay += __shfl_xor(ay, 32);
        if (lane == 0) {
            float dr = dnorm[wid];
            int rks = gat[wid];
            if (rks >= 0) {
                float cf = (float)(diag[wid] + 1) * dr;
                float2 zs = Z2[rks];
                ax += cf * zs.x;
                ay += cf * zs.y;
            }
            float v0 = dr * ax;
            float v1 = dr * ay;
            float m = fmaxf(v0, v1);
            float e0 = __expf(v0 - m);
            float e1 = __expf(v1 - m);
            float inv = 1.0f / (e0 + e1);
            float2 r;
            r.x = e0 * inv;
            r.y = e1 * inv;
            ((float2*)out)[wid] = r;
        }
    }
}

struct GcnP {
    const u16* ellA; const int* cntA; const int* diagA; const float* dnA;
    const float* Z1; float* X1; float* sc1; int* rank1; int* idx1;
    u16* ellS; int* cntS; int* diagS; float* dnS;
    float* Z2f; float* X2; float* sc2; int* rank2; int* idx2;
    float* Z3f; float* Z4r;
    const float* W2; const float* W3; const float* W4; const float* s1; const float* s2;
    float* out;
};

// ---------------------------------------------------------------------------
// Cooperative pipeline: everything after the A-scan, grid.sync between phases.
// ---------------------------------------------------------------------------
__global__ __launch_bounds__(256, 4) void gcn_pipeline(GcnP p)
{
    cg::grid_group grid = cg::this_grid();
    __shared__ TkS sm;
    int tid = threadIdx.x;
    int bid = blockIdx.x;
    int lane = tid & 63;
    int gwave = (bid * 256 + tid) >> 6;
    int nwaves = ((int)gridDim.x * 256) >> 6;

    // P1: GCN1 spmm + pool1 scores
    spmm_phase<false, false, false, true>(p.ellA, p.cntA, p.diagA, p.dnA, p.Z1,
        (const int*)0, (const int*)0, p.X1, p.sc1, p.s1, (const float*)0, (float*)0,
        NNODES, STRA, gwave, nwaves, lane);
    grid.sync();

    // P2: pool1 top-k (block 0) + Z2f = X1@W2 over ALL rows (other blocks)
    if (bid == 0) topk_block0(sm, p.sc1, NNODES, KP1, p.rank1, p.idx1, tid);
    else gemm32(p.X1, p.W2, p.Z2f, NNODES, FH, (bid - 1) * 256 + tid, ((int)gridDim.x - 1) * 256);
    grid.sync();

    // P3: subgraph ELL
    subell_phase(p.ellA, p.cntA, p.diagA, p.idx1, p.rank1, p.ellS, p.cntS, p.diagS, p.dnS,
        KP1, STRA, STRS, gwave, nwaves, lane);
    grid.sync();

    // P4: GCN2 on subgraph (Z gathered from full space via idx1)
    spmm_phase<true, false, false, true>(p.ellS, p.cntS, p.diagS, p.dnS, p.Z2f,
        p.idx1, (const int*)0, p.X2, p.sc2, p.s2, (const float*)0, (float*)0,
        KP1, STRS, gwave, nwaves, lane);
    grid.sync();

    // P5: pool2 top-k (block 0) + Z3f = X2@W3 (other blocks)
    if (bid == 0) topk_block0(sm, p.sc2, KP1, KP2, p.rank2, p.idx2, tid);
    else gemm32(p.X2, p.W3, p.Z3f, KP1, FH, (bid - 1) * 256 + tid, ((int)gridDim.x - 1) * 256);
    grid.sync();

    // P6: GCN3 with pool2 mask + fused W4 epilogue -> Z4r
    spmm_phase<false, true, true, false>(p.ellS, p.cntS, p.diagS, p.dnS, p.Z3f,
        (const int*)0, p.rank2, (float*)0, (float*)0, (const float*)0, p.W4, p.Z4r,
        KP1, STRS, gwave, nwaves, lane);
    grid.sync();

    // P7: GCN4 + softmax (unpool1 folded into rank1 gather)
    spmmout_phase(p.ellA, p.cntA, p.diagA, p.dnA, p.Z4r, p.rank1, p.out,
        NNODES, STRA, gwave, nwaves, lane);
}

// ---------------------------------------------------------------------------
// Fallback path: separate kernels (proven round-0 structure), used only if the
// cooperative launch is rejected at enqueue time.
// ---------------------------------------------------------------------------
__global__ __launch_bounds__(256) void k_spmm(const u16* __restrict__ ell, const int* __restrict__ rowcnt,
        const int* __restrict__ diag, const float* __restrict__ dnorm, const float* __restrict__ Z,
        const int* __restrict__ remap, const int* __restrict__ maskp,
        float* __restrict__ X, float* __restrict__ scores, const float* __restrict__ svec,
        const float* __restrict__ W4p, float* __restrict__ z4out, int n, int stride, int mode)
{
    int gwave = ((int)blockIdx.x * 256 + (int)threadIdx.x) >> 6;
    int nwaves = ((int)gridDim.x * 256) >> 6;
    int lane = threadIdx.x & 63;
    if (mode == 0)
        spmm_phase<false, false, false, true>(ell, rowcnt, diag, dnorm, Z, remap, maskp,
            X, scores, svec, W4p, z4out, n, stride, gwave, nwaves, lane);
    else if (mode == 1)
        spmm_phase<true, false, false, true>(ell, rowcnt, diag, dnorm, Z, remap, maskp,
            X, scores, svec, W4p, z4out, n, stride, gwave, nwaves, lane);
    else
        spmm_phase<false, true, true, false>(ell, rowcnt, diag, dnorm, Z, remap, maskp,
            X, scores, svec, W4p, z4out, n, stride, gwave, nwaves, lane);
}

__global__ __launch_bounds__(256) void k_topk_gemm(const float* __restrict__ scores, int n, int K,
        int* __restrict__ rank, int* __restrict__ idxlist,
        const float* __restrict__ Xf, const float* __restrict__ Wf, float* __restrict__ Zf, int kf)
{
    __shared__ TkS sm;
    if (blockIdx.x == 0) topk_block0(sm, scores, n, K, rank, idxlist, threadIdx.x);
    else gemm32(Xf, Wf, Zf, n, kf, ((int)blockIdx.x - 1) * 256 + threadIdx.x, ((int)gridDim.x - 1) * 256);
}

__global__ __launch_bounds__(256) void k_subell(const u16* __restrict__ ellA, const int* __restrict__ rowcntA,
        const int* __restrict__ diagA, const int* __restrict__ idx1, const int* __restrict__ rank1,
        u16* __restrict__ ellS, int* __restrict__ rowcntS, int* __restrict__ diagS, float* __restrict__ dnormS,
        int k1, int strideA, int strideS)
{
    int gwave = ((int)blockIdx.x * 256 + (int)threadIdx.x) >> 6;
    int nwaves = ((int)gridDim.x * 256) >> 6;
    subell_phase(ellA, rowcntA, diagA, idx1, rank1, ellS, rowcntS, diagS, dnormS,
        k1, strideA, strideS, gwave, nwaves, threadIdx.x & 63);
}

__global__ __launch_bounds__(256) void k_spmmout(const u16* __restrict__ ell, const int* __restrict__ rowcnt,
        const int* __restrict__ diag, const float* __restrict__ dnorm, const float* __restrict__ Zr,
        const int* __restrict__ gat, float* __restrict__ out, int n, int stride)
{
    int gwave = ((int)blockIdx.x * 256 + (int)threadIdx.x) >> 6;
    int nwaves = ((int)gridDim.x * 256) >> 6;
    spmmout_phase(ell, rowcnt, diag, dnorm, Zr, gat, out, n, stride, gwave, nwaves, threadIdx.x & 63);
}

#define CARVE(type, name, bytes) \
    type name = (type)wp; wp += (((size_t)(bytes)) + 255) & ~((size_t)255);

extern "C" void kernel_launch(void* const* d_in, const int* in_sizes, int n_in,
                              void* d_out, int out_size, void* d_ws, size_t ws_size,
                              hipStream_t stream)
{
    const float* x  = (const float*)d_in[0];
    const float* a  = (const float*)d_in[1];
    const float* W1 = (const float*)d_in[2];
    const float* W2 = (const float*)d_in[3];
    const float* W3 = (const float*)d_in[4];
    const float* W4 = (const float*)d_in[5];
    const float* s1 = (const float*)d_in[6];
    const float* s2 = (const float*)d_in[7];
    float* out = (float*)d_out;
    (void)in_sizes; (void)n_in; (void)out_size; (void)ws_size;

    char* wp = (char*)d_ws;
    CARVE(u16*,   ellA,  (size_t)NNODES * STRA * sizeof(u16));   // 5.2 MB
    CARVE(int*,   cntA,  NNODES * sizeof(int));
    CARVE(int*,   diagA, NNODES * sizeof(int));
    CARVE(float*, dnA,   NNODES * sizeof(float));
    CARVE(float*, Z1,    (size_t)NNODES * FH * sizeof(float));
    CARVE(float*, X1,    (size_t)NNODES * FH * sizeof(float));
    CARVE(float*, sc1,   NNODES * sizeof(float));
    CARVE(int*,   rank1, NNODES * sizeof(int));
    CARVE(int*,   idx1,  NNODES * sizeof(int));
    CARVE(u16*,   ellS,  (size_t)KP1 * STRS * sizeof(u16));      // 2.6 MB
    CARVE(int*,   cntS,  KP1 * sizeof(int));
    CARVE(int*,   diagS, KP1 * sizeof(int));
    CARVE(float*, dnS,   KP1 * sizeof(float));
    CARVE(float*, Z2f,   (size_t)NNODES * FH * sizeof(float));   // X1@W2 over ALL rows
    CARVE(float*, X2,    (size_t)KP1 * FH * sizeof(float));
    CARVE(float*, sc2,   KP1 * sizeof(float));
    CARVE(int*,   rank2, KP1 * sizeof(int));
    CARVE(int*,   idx2,  KP1 * sizeof(int));
    CARVE(float*, Z3f,   (size_t)KP1 * FH * sizeof(float));      // X2@W3 over all pooled rows
    CARVE(float*, Z4r,   (size_t)KP1 * COUT * sizeof(float));    // rank-space X3@W4

    // 1) one full 256MB pass -> ELL + co-launched Z1 = x@W1
    build_ell<<<NNODES + (NNODES * FH) / 256, 256, 0, stream>>>(
        a, NNODES, STRA, ellA, cntA, diagA, dnA, x, W1, Z1, FIN);

    // 2) cooperative grid size: query once, clamp to validated co-residency
    static int g_cgrid = 0;
    if (g_cgrid == 0) {
        int maxb = 0;
        if (hipOccupancyMaxActiveBlocksPerMultiprocessor(&maxb, (const void*)gcn_pipeline, 256, 0)
                != hipSuccess || maxb <= 0)
            maxb = 2;  // conservative
        int ncu = 256;
        hipDeviceProp_t props;
        if (hipGetDeviceProperties(&props, 0) == hipSuccess && props.multiProcessorCount > 0)
            ncu = props.multiProcessorCount;
        long g = (long)maxb * (long)ncu;
        if (g > CGRID_MAX) g = CGRID_MAX;
        if (g < 2) g = 2;
        g_cgrid = (int)g;
    }

    GcnP pp;
    pp.ellA = ellA; pp.cntA = cntA; pp.diagA = diagA; pp.dnA = dnA;
    pp.Z1 = Z1; pp.X1 = X1; pp.sc1 = sc1; pp.rank1 = rank1; pp.idx1 = idx1;
    pp.ellS = ellS; pp.cntS = cntS; pp.diagS = diagS; pp.dnS = dnS;
    pp.Z2f = Z2f; pp.X2 = X2; pp.sc2 = sc2; pp.rank2 = rank2; pp.idx2 = idx2;
    pp.Z3f = Z3f; pp.Z4r = Z4r;
    pp.W2 = W2; pp.W3 = W3; pp.W4 = W4; pp.s1 = s1; pp.s2 = s2;
    pp.out = out;
    void* kargs[] = { (void*)&pp };
    hipError_t ce = hipLaunchCooperativeKernel((const void*)gcn_pipeline,
                                               dim3((unsigned)g_cgrid), dim3(256), kargs, 0u, stream);
    if (ce != hipSuccess) {
        // Fallback: proven multi-kernel pipeline (round-0 structure)
        k_spmm<<<NNODES / 4, 256, 0, stream>>>(ellA, cntA, diagA, dnA, Z1,
            (const int*)0, (const int*)0, X1, sc1, s1, (const float*)0, (float*)0, NNODES, STRA, 0);
        k_topk_gemm<<<1 + (NNODES * FH) / 256, 256, 0, stream>>>(
            sc1, NNODES, KP1, rank1, idx1, X1, W2, Z2f, FH);
        k_subell<<<KP1 / 4, 256, 0, stream>>>(ellA, cntA, diagA, idx1, rank1,
            ellS, cntS, diagS, dnS, KP1, STRA, STRS);
        k_spmm<<<KP1 / 4, 256, 0, stream>>>(ellS, cntS, diagS, dnS, Z2f,
            idx1, (const int*)0, X2, sc2, s2, (const float*)0, (float*)0, KP1, STRS, 1);
        k_topk_gemm<<<1 + (KP1 * FH) / 256, 256, 0, stream>>>(
            sc2, KP1, KP2, rank2, idx2, X2, W3, Z3f, FH);
        k_spmm<<<KP1 / 4, 256, 0, stream>>>(ellS, cntS, diagS, dnS, Z3f,
            (const int*)0, rank2, (float*)0, (float*)0, (const float*)0, W4, Z4r, KP1, STRS, 2);
        k_spmmout<<<NNODES / 4, 256, 0, stream>>>(ellA, cntA, diagA, dnA, Z4r, rank1, out, NNODES, STRA);
    }
}

// Round 3
// 667.851 us; speedup vs baseline: 1.2817x; 1.2817x over previous
//
#include <hip/hip_runtime.h>
#include <stdint.h>

#define NNODES 8192
#define KP1 4096
#define KP2 2048
#define FIN 16
#define FH 32
#define COUT 2
#define STRA 320   // max off-diag nnz/row; mean ~163, sigma ~12.6 -> >12 sigma headroom
#define STRS 320
#define CGRID_MAX 1024

typedef unsigned short u16;
typedef unsigned int u32;

// ---------------------------------------------------------------------------
// Kernel 1: blocks [0,n) stream the 256MB dense adjacency ONCE (float4,
// coalesced, block-local LDS counting) -> u16 ELL; blocks [n,...) compute
// Z1 = x @ W1 (independent co-launched work). Also zero-inits the grid
// barrier state (bar[0]=arrive count, bar[32]=generation; separate lines).
// ---------------------------------------------------------------------------
__global__ __launch_bounds__(256) void build_ell(const float* __restrict__ A, int n, int stride,
        u16* __restrict__ ell, int* __restrict__ rowcnt, int* __restrict__ diag, float* __restrict__ dnorm,
        const float* __restrict__ Xf, const float* __restrict__ Wf, float* __restrict__ Zf, int kf,
        u32* __restrict__ bar)
{
    if ((int)blockIdx.x >= n) {
        if ((int)blockIdx.x == n && threadIdx.x == 0) { bar[0] = 0u; bar[32] = 0u; }
        int t = ((int)blockIdx.x - n) * 256 + threadIdx.x;
        int i = t >> 5;
        int f = t & 31;
        const float* xr = Xf + (size_t)i * kf;
        float acc = 0.0f;
        for (int k = 0; k < kf; ++k) acc += xr[k] * Wf[k * 32 + f];
        Zf[t] = acc;
        return;
    }
    __shared__ int cnt;
    __shared__ int dg;
    int row = blockIdx.x;
    if (threadIdx.x == 0) { cnt = 0; dg = 0; }
    __syncthreads();
    const float4* arow4 = (const float4*)(A + (size_t)row * n);
    u16* erow = ell + (size_t)row * stride;
    int n4 = n >> 2;
    for (int c4 = threadIdx.x; c4 < n4; c4 += 256) {
        float4 v = arow4[c4];
        if (v.x == 0.0f && v.y == 0.0f && v.z == 0.0f && v.w == 0.0f) continue;
        int cb = c4 << 2;
        if (v.x != 0.0f) {
            if (cb == row) dg = 1;
            else { int p = atomicAdd(&cnt, 1); if (p < stride) erow[p] = (u16)cb; }
        }
        if (v.y != 0.0f) {
            int c = cb + 1;
            if (c == row) dg = 1;
            else { int p = atomicAdd(&cnt, 1); if (p < stride) erow[p] = (u16)c; }
        }
        if (v.z != 0.0f) {
            int c = cb + 2;
            if (c == row) dg = 1;
            else { int p = atomicAdd(&cnt, 1); if (p < stride) erow[p] = (u16)c; }
        }
        if (v.w != 0.0f) {
            int c = cb + 3;
            if (c == row) dg = 1;
            else { int p = atomicAdd(&cnt, 1); if (p < stride) erow[p] = (u16)c; }
        }
    }
    __syncthreads();
    if (threadIdx.x == 0) {
        int cf = cnt;
        rowcnt[row] = cf < stride ? cf : stride;
        diag[row] = dg;
        dnorm[row] = rsqrtf((float)(cf + dg + 1) + 1e-10f);
    }
}

// ---------------------------------------------------------------------------
// Custom grid barrier. One fetch_add per block on arrival; spinners poll the
// generation word with agent-scope atomic LOADS (no RMW; plain loads could
// spin forever on a stale non-coherent per-XCD L2 line) + s_sleep backoff.
// __threadfence() release/acquire handles cross-XCD data visibility.
// ---------------------------------------------------------------------------
__device__ __forceinline__ void gbar(u32* cnt, u32* gen, int nblk)
{
    __syncthreads();
    if (threadIdx.x == 0) {
        __threadfence();   // release: prior global writes visible device-wide
        u32 g = __hip_atomic_load(gen, __ATOMIC_RELAXED, __HIP_MEMORY_SCOPE_AGENT);
        u32 a = __hip_atomic_fetch_add(cnt, 1u, __ATOMIC_ACQ_REL, __HIP_MEMORY_SCOPE_AGENT);
        if (a == (u32)(nblk - 1)) {
            __hip_atomic_store(cnt, 0u, __ATOMIC_RELAXED, __HIP_MEMORY_SCOPE_AGENT);
            __hip_atomic_fetch_add(gen, 1u, __ATOMIC_RELEASE, __HIP_MEMORY_SCOPE_AGENT);
        } else {
            while (__hip_atomic_load(gen, __ATOMIC_RELAXED, __HIP_MEMORY_SCOPE_AGENT) == g)
                __builtin_amdgcn_s_sleep(16);   // ~1024 cyc poll period
        }
        __threadfence();   // acquire: see other blocks' writes
    }
    __syncthreads();
}

// ---------------------------------------------------------------------------
// Shared phase bodies (used by the cooperative pipeline AND the fallback path)
// ---------------------------------------------------------------------------
struct TkS {
    u32 hist[4][256];
    u32 wsum[4];
    u32 pref;
    u32 rem;
};  // 4,120 B

__device__ __forceinline__ u32 km_of(float f)
{
    u32 u = __float_as_uint(f);
    u32 m;
    if (u & 0x80000000u) m = ~u; else m = u | 0x80000000u;  // monotone asc in float
    return ~m;                                              // asc in km == desc in score
}

// Exact top-K (jax.lax.top_k set semantics: value desc, index-asc ties).
// Block-local: call from exactly one block (256 threads). Keys recomputed from
// scores each pass (L1-resident) instead of an LDS cache.
__device__ void topk_block0(TkS& s, const float* __restrict__ scores, int n, int K,
                            int* __restrict__ rank, int* __restrict__ idxlist, int tid)
{
    int wv = tid >> 6;
    int lane = tid & 63;
    int per = n >> 8;       // 32 (n=8192) or 16 (n=4096)
    int base = tid * per;
    if (tid == 0) { s.pref = 0u; s.rem = (u32)K; }
    __syncthreads();
    for (int bp = 3; bp >= 0; --bp) {
        s.hist[0][tid] = 0u;
        s.hist[1][tid] = 0u;
        s.hist[2][tid] = 0u;
        s.hist[3][tid] = 0u;
        __syncthreads();                 // hist zeroed; prev-iter pref visible
        u32 maskhi = 0u;
        if (bp < 3) maskhi = 0xFFFFFFFFu << ((bp + 1) * 8);
        u32 pref = s.pref;
        u32 rem = s.rem;
        for (int e = 0; e < per; ++e) {
            u32 km = km_of(scores[base + e]);
            if ((km & maskhi) == pref) atomicAdd(&s.hist[wv][(km >> (bp * 8)) & 255u], 1u);
        }
        __syncthreads();                 // atomics done
        u32 tot = s.hist[0][tid] + s.hist[1][tid] + s.hist[2][tid] + s.hist[3][tid];
        u32 vv = tot;
        u32 t2;
        t2 = __shfl(vv, lane - 1);  if (lane >= 1)  vv += t2;
        t2 = __shfl(vv, lane - 2);  if (lane >= 2)  vv += t2;
        t2 = __shfl(vv, lane - 4);  if (lane >= 4)  vv += t2;
        t2 = __shfl(vv, lane - 8);  if (lane >= 8)  vv += t2;
        t2 = __shfl(vv, lane - 16); if (lane >= 16) vv += t2;
        t2 = __shfl(vv, lane - 32); if (lane >= 32) vv += t2;
        if (lane == 63) s.wsum[wv] = vv;
        __syncthreads();                 // wave sums visible
        u32 add = 0u;
        if (wv > 0) add += s.wsum[0];
        if (wv > 1) add += s.wsum[1];
        if (wv > 2) add += s.wsum[2];
        u32 cum = vv + add;
        if (tot != 0u && cum >= rem && cum - tot < rem) {  // unique boundary bin
            s.pref = pref | ((u32)tid << (bp * 8));
            s.rem = rem - (cum - tot);
        }
    }
    __syncthreads();
    u32 T = s.pref;        // K-th smallest km
    u32 need_eq = s.rem;   // how many km==T to take (lowest node index first)
    u32 run = 0u;          // high16 = #(km<T), low16 = #(km==T)
    for (int e = 0; e < per; ++e) {
        u32 km = km_of(scores[base + e]);
        if (km < T) run += 0x10000u;
        else if (km == T) run += 1u;
    }
    u32 v2 = run;
    u32 t3;
    t3 = __shfl(v2, lane - 1);  if (lane >= 1)  v2 += t3;
    t3 = __shfl(v2, lane - 2);  if (lane >= 2)  v2 += t3;
    t3 = __shfl(v2, lane - 4);  if (lane >= 4)  v2 += t3;
    t3 = __shfl(v2, lane - 8);  if (lane >= 8)  v2 += t3;
    t3 = __shfl(v2, lane - 16); if (lane >= 16) v2 += t3;
    t3 = __shfl(v2, lane - 32); if (lane >= 32) v2 += t3;
    if (lane == 63) s.wsum[wv] = v2;
    __syncthreads();
    u32 add2 = 0u;
    if (wv > 0) add2 += s.wsum[0];
    if (wv > 1) add2 += s.wsum[1];
    if (wv > 2) add2 += s.wsum[2];
    u32 cur = v2 + add2 - run;   // exclusive prefix for this thread's chunk
    for (int e = 0; e < per; ++e) {
        int v = base + e;
        u32 km = km_of(scores[v]);
        u32 ltb = cur >> 16;
        u32 eqb = cur & 0xFFFFu;
        u32 eqs = eqb < need_eq ? eqb : need_eq;
        int sel = 0;
        if (km < T) { sel = 1; cur += 0x10000u; }
        else if (km == T) { if (eqb < need_eq) sel = 1; cur += 1u; }
        if (sel) {
            int r = (int)(ltb + eqs);
            rank[v] = r;
            idxlist[r] = v;
        } else {
            rank[v] = -1;
        }
    }
}

// Dense Zf = Xf @ Wf (fout=32), grid-stride over elements.
__device__ __forceinline__ void gemm32(const float* __restrict__ Xf, const float* __restrict__ Wf,
                                       float* __restrict__ Zf, int rows, int kf, int t0, int tstr)
{
    int tot = rows * 32;
    for (int t = t0; t < tot; t += tstr) {
        int i = t >> 5;
        int f = t & 31;
        const float* xr = Xf + (size_t)i * kf;
        float acc = 0.0f;
        for (int k = 0; k < kf; ++k) acc += xr[k] * Wf[k * 32 + f];
        Zf[t] = acc;
    }
}

// SpMM (F=32) + relu; one wave per row, 8 lanes per neighbor, float4 per lane.
template<bool REMAP, bool MASK, bool FW4, bool SC>
__device__ __forceinline__ void spmm_phase(
        const u16* __restrict__ ell, const int* __restrict__ rowcnt,
        const int* __restrict__ diag, const float* __restrict__ dnorm,
        const float* __restrict__ Z, const int* __restrict__ remap, const int* __restrict__ maskp,
        float* __restrict__ X, float* __restrict__ scores, const float* __restrict__ svec,
        const float* __restrict__ W4p, float* __restrict__ z4out,
        int n, int stride, int gwave, int nwaves, int lane)
{
    int g = lane >> 3;   // neighbor sub-slot 0..7
    int q = lane & 7;    // feature quad 0..7
    for (int wid = gwave; wid < n; wid += nwaves) {
        int cnt = rowcnt[wid];
        const u16* erow = ell + (size_t)wid * stride;
        float ax = 0.0f, ay = 0.0f, az = 0.0f, aw = 0.0f;
        for (int it = g; it < cnt; it += 8) {
            int c = erow[it];
            if (MASK && maskp[c] < 0) continue;
            int zc = REMAP ? remap[c] : c;
            float dn = dnorm[c];
            const float4* zp = (const float4*)(Z + (size_t)zc * 32);
            float4 zv = zp[q];
            ax += dn * zv.x;
            ay += dn * zv.y;
            az += dn * zv.z;
            aw += dn * zv.w;
        }
        ax += __shfl_xor(ax, 8);  ay += __shfl_xor(ay, 8);
        az += __shfl_xor(az, 8);  aw += __shfl_xor(aw, 8);
        ax += __shfl_xor(ax, 16); ay += __shfl_xor(ay, 16);
        az += __shfl_xor(az, 16); aw += __shfl_xor(aw, 16);
        ax += __shfl_xor(ax, 32); ay += __shfl_xor(ay, 32);
        az += __shfl_xor(az, 32); aw += __shfl_xor(aw, 32);
        if (g == 0) {   // lanes 0..7 hold the full sum for feature quad q
            float dr = dnorm[wid];
            bool selfok = !(MASK && maskp[wid] < 0);
            if (selfok) {
                int zc = REMAP ? remap[wid] : wid;
                const float4* zp = (const float4*)(Z + (size_t)zc * 32);
                float4 zv = zp[q];
                float cf = (float)(diag[wid] + 1) * dr;
                ax += cf * zv.x;
                ay += cf * zv.y;
                az += cf * zv.z;
                aw += cf * zv.w;
            }
            float ox = fmaxf(dr * ax, 0.0f);
            float oy = fmaxf(dr * ay, 0.0f);
            float oz = fmaxf(dr * az, 0.0f);
            float ow = fmaxf(dr * aw, 0.0f);
            if (FW4) {
                int kb = q * 4;
                float p0 = ox * W4p[(kb + 0) * 2 + 0] + oy * W4p[(kb + 1) * 2 + 0]
                         + oz * W4p[(kb + 2) * 2 + 0] + ow * W4p[(kb + 3) * 2 + 0];
                float p1 = ox * W4p[(kb + 0) * 2 + 1] + oy * W4p[(kb + 1) * 2 + 1]
                         + oz * W4p[(kb + 2) * 2 + 1] + ow * W4p[(kb + 3) * 2 + 1];
                p0 += __shfl_xor(p0, 1);
                p1 += __shfl_xor(p1, 1);
                p0 += __shfl_xor(p0, 2);
                p1 += __shfl_xor(p1, 2);
                p0 += __shfl_xor(p0, 4);
                p1 += __shfl_xor(p1, 4);
                if (q == 0) {
                    float2 r;
                    r.x = p0;
                    r.y = p1;
                    ((float2*)z4out)[wid] = r;
                }
            } else {
                float4 o;
                o.x = ox; o.y = oy; o.z = oz; o.w = ow;
                float4* xp = (float4*)(X + (size_t)wid * 32);
                xp[q] = o;
                if (SC) {
                    const float4* sp = (const float4*)svec;
                    float4 sv = sp[q];
                    float pp = o.x * sv.x + o.y * sv.y + o.z * sv.z + o.w * sv.w;
                    pp += __shfl_xor(pp, 1);
                    pp += __shfl_xor(pp, 2);
                    pp += __shfl_xor(pp, 4);
                    if (q == 0) scores[wid] = pp;
                }
            }
        }
    }
}

// Subgraph ELL for A1p = a[idx1][:,idx1]; wave-compaction via ballot.
__device__ __forceinline__ void subell_phase(const u16* __restrict__ ellA, const int* __restrict__ rowcntA,
        const int* __restrict__ diagA, const int* __restrict__ idx1, const int* __restrict__ rank1,
        u16* __restrict__ ellS, int* __restrict__ rowcntS, int* __restrict__ diagS, float* __restrict__ dnormS,
        int k1, int strideA, int strideS, int gwave, int nwaves, int lane)
{
    for (int wid = gwave; wid < k1; wid += nwaves) {
        int r = idx1[wid];
        int cnt = rowcntA[r];
        const u16* erow = ellA + (size_t)r * strideA;
        u16* srow = ellS + (size_t)wid * strideS;
        int outn = 0;
        for (int t0 = 0; t0 < cnt; t0 += 64) {
            int it = t0 + lane;
            int rk = -1;
            if (it < cnt) rk = rank1[erow[it]];
            unsigned long long b = __ballot(rk >= 0);
            int ofs = __popcll(b & ((1ull << lane) - 1ull));
            if (rk >= 0) srow[outn + ofs] = (u16)rk;
            outn += __popcll(b);
        }
        if (lane == 0) {
            int dg = diagA[r];
            rowcntS[wid] = outn;
            diagS[wid] = dg;
            dnormS[wid] = rsqrtf((float)(outn + dg + 1) + 1e-10f);
        }
    }
}

// Final SpMM (F=2) + 2-way softmax; unpool1 folded into the gat[] gather.
__device__ __forceinline__ void spmmout_phase(const u16* __restrict__ ell, const int* __restrict__ rowcnt,
        const int* __restrict__ diag, const float* __restrict__ dnorm, const float* __restrict__ Zr,
        const int* __restrict__ gat, float* __restrict__ out, int n, int stride,
        int gwave, int nwaves, int lane)
{
    const float2* Z2 = (const float2*)Zr;
    for (int wid = gwave; wid < n; wid += nwaves) {
        int cnt = rowcnt[wid];
        const u16* erow = ell + (size_t)wid * stride;
        float ax = 0.0f, ay = 0.0f;
        for (int it = lane; it < cnt; it += 64) {
            int c = erow[it];
            int rk = gat[c];
            if (rk >= 0) {
                float dn = dnorm[c];
                float2 zv = Z2[rk];
                ax += dn * zv.x;
                ay += dn * zv.y;
            }
        }
        ax += __shfl_xor(ax, 1);  ay += __shfl_xor(ay, 1);
        ax += __shfl_xor(ax, 2);  ay += __shfl_xor(ay, 2);
        ax += __shfl_xor(ax, 4);  ay += __shfl_xor(ay, 4);
        ax += __shfl_xor(ax, 8);  ay += __shfl_xor(ay, 8);
        ax += __shfl_xor(ax, 16); ay += __shfl_xor(ay, 16);
        ax += __shfl_xor(ax, 32); ay += __shfl_xor(ay, 32);
        if (lane == 0) {
            float dr = dnorm[wid];
            int rks = gat[wid];
            if (rks >= 0) {
                float cf = (float)(diag[wid] + 1) * dr;
                float2 zs = Z2[rks];
                ax += cf * zs.x;
                ay += cf * zs.y;
            }
            float v0 = dr * ax;
            float v1 = dr * ay;
            float m = fmaxf(v0, v1);
            float e0 = __expf(v0 - m);
            float e1 = __expf(v1 - m);
            float inv = 1.0f / (e0 + e1);
            float2 r;
            r.x = e0 * inv;
            r.y = e1 * inv;
            ((float2*)out)[wid] = r;
        }
    }
}

struct GcnP {
    const u16* ellA; const int* cntA; const int* diagA; const float* dnA;
    const float* Z1; float* X1; float* sc1; int* rank1; int* idx1;
    u16* ellS; int* cntS; int* diagS; float* dnS;
    float* Z2f; float* X2; float* sc2; int* rank2; int* idx2;
    float* Z3f; float* Z4r;
    const float* W2; const float* W3; const float* W4; const float* s1; const float* s2;
    float* out;
    u32* bar;
};

// ---------------------------------------------------------------------------
// Cooperative pipeline: everything after the A-scan, custom gbar between
// phases (cg::grid_group::sync measured ~130us/sync at 1024 blocks — r2).
// ---------------------------------------------------------------------------
__global__ __launch_bounds__(256, 4) void gcn_pipeline(GcnP p)
{
    __shared__ TkS sm;
    int tid = threadIdx.x;
    int bid = blockIdx.x;
    int lane = tid & 63;
    int gwave = (bid * 256 + tid) >> 6;
    int nwaves = ((int)gridDim.x * 256) >> 6;
    int nblk = (int)gridDim.x;
    u32* bcnt = p.bar;
    u32* bgen = p.bar + 32;   // separate 128B line from the arrive counter

    // P1: GCN1 spmm + pool1 scores
    spmm_phase<false, false, false, true>(p.ellA, p.cntA, p.diagA, p.dnA, p.Z1,
        (const int*)0, (const int*)0, p.X1, p.sc1, p.s1, (const float*)0, (float*)0,
        NNODES, STRA, gwave, nwaves, lane);
    gbar(bcnt, bgen, nblk);

    // P2: pool1 top-k (block 0) + Z2f = X1@W2 over ALL rows (other blocks)
    if (bid == 0) topk_block0(sm, p.sc1, NNODES, KP1, p.rank1, p.idx1, tid);
    else gemm32(p.X1, p.W2, p.Z2f, NNODES, FH, (bid - 1) * 256 + tid, ((int)gridDim.x - 1) * 256);
    gbar(bcnt, bgen, nblk);

    // P3: subgraph ELL
    subell_phase(p.ellA, p.cntA, p.diagA, p.idx1, p.rank1, p.ellS, p.cntS, p.diagS, p.dnS,
        KP1, STRA, STRS, gwave, nwaves, lane);
    gbar(bcnt, bgen, nblk);

    // P4: GCN2 on subgraph (Z gathered from full space via idx1)
    spmm_phase<true, false, false, true>(p.ellS, p.cntS, p.diagS, p.dnS, p.Z2f,
        p.idx1, (const int*)0, p.X2, p.sc2, p.s2, (const float*)0, (float*)0,
        KP1, STRS, gwave, nwaves, lane);
    gbar(bcnt, bgen, nblk);

    // P5: pool2 top-k (block 0) + Z3f = X2@W3 (other blocks)
    if (bid == 0) topk_block0(sm, p.sc2, KP1, KP2, p.rank2, p.idx2, tid);
    else gemm32(p.X2, p.W3, p.Z3f, KP1, FH, (bid - 1) * 256 + tid, ((int)gridDim.x - 1) * 256);
    gbar(bcnt, bgen, nblk);

    // P6: GCN3 with pool2 mask + fused W4 epilogue -> Z4r
    spmm_phase<false, true, true, false>(p.ellS, p.cntS, p.diagS, p.dnS, p.Z3f,
        (const int*)0, p.rank2, (float*)0, (float*)0, (const float*)0, p.W4, p.Z4r,
        KP1, STRS, gwave, nwaves, lane);
    gbar(bcnt, bgen, nblk);

    // P7: GCN4 + softmax (unpool1 folded into rank1 gather)
    spmmout_phase(p.ellA, p.cntA, p.diagA, p.dnA, p.Z4r, p.rank1, p.out,
        NNODES, STRA, gwave, nwaves, lane);
}

// ---------------------------------------------------------------------------
// Fallback path: separate kernels (proven round-0 structure), used only if the
// cooperative launch is rejected at enqueue time.
// ---------------------------------------------------------------------------
__global__ __launch_bounds__(256) void k_spmm(const u16* __restrict__ ell, const int* __restrict__ rowcnt,
        const int* __restrict__ diag, const float* __restrict__ dnorm, const float* __restrict__ Z,
        const int* __restrict__ remap, const int* __restrict__ maskp,
        float* __restrict__ X, float* __restrict__ scores, const float* __restrict__ svec,
        const float* __restrict__ W4p, float* __restrict__ z4out, int n, int stride, int mode)
{
    int gwave = ((int)blockIdx.x * 256 + (int)threadIdx.x) >> 6;
    int nwaves = ((int)gridDim.x * 256) >> 6;
    int lane = threadIdx.x & 63;
    if (mode == 0)
        spmm_phase<false, false, false, true>(ell, rowcnt, diag, dnorm, Z, remap, maskp,
            X, scores, svec, W4p, z4out, n, stride, gwave, nwaves, lane);
    else if (mode == 1)
        spmm_phase<true, false, false, true>(ell, rowcnt, diag, dnorm, Z, remap, maskp,
            X, scores, svec, W4p, z4out, n, stride, gwave, nwaves, lane);
    else
        spmm_phase<false, true, true, false>(ell, rowcnt, diag, dnorm, Z, remap, maskp,
            X, scores, svec, W4p, z4out, n, stride, gwave, nwaves, lane);
}

__global__ __launch_bounds__(256) void k_topk_gemm(const float* __restrict__ scores, int n, int K,
        int* __restrict__ rank, int* __restrict__ idxlist,
        const float* __restrict__ Xf, const float* __restrict__ Wf, float* __restrict__ Zf, int kf)
{
    __shared__ TkS sm;
    if (blockIdx.x == 0) topk_block0(sm, scores, n, K, rank, idxlist, threadIdx.x);
    else gemm32(Xf, Wf, Zf, n, kf, ((int)blockIdx.x - 1) * 256 + threadIdx.x, ((int)gridDim.x - 1) * 256);
}

__global__ __launch_bounds__(256) void k_subell(const u16* __restrict__ ellA, const int* __restrict__ rowcntA,
        const int* __restrict__ diagA, const int* __restrict__ idx1, const int* __restrict__ rank1,
        u16* __restrict__ ellS, int* __restrict__ rowcntS, int* __restrict__ diagS, float* __restrict__ dnormS,
        int k1, int strideA, int strideS)
{
    int gwave = ((int)blockIdx.x * 256 + (int)threadIdx.x) >> 6;
    int nwaves = ((int)gridDim.x * 256) >> 6;
    subell_phase(ellA, rowcntA, diagA, idx1, rank1, ellS, rowcntS, diagS, dnormS,
        k1, strideA, strideS, gwave, nwaves, threadIdx.x & 63);
}

__global__ __launch_bounds__(256) void k_spmmout(const u16* __restrict__ ell, const int* __restrict__ rowcnt,
        const int* __restrict__ diag, const float* __restrict__ dnorm, const float* __restrict__ Zr,
        const int* __restrict__ gat, float* __restrict__ out, int n, int stride)
{
    int gwave = ((int)blockIdx.x * 256 + (int)threadIdx.x) >> 6;
    int nwaves = ((int)gridDim.x * 256) >> 6;
    spmmout_phase(ell, rowcnt, diag, dnorm, Zr, gat, out, n, stride, gwave, nwaves, threadIdx.x & 63);
}

#define CARVE(type, name, bytes) \
    type name = (type)wp; wp += (((size_t)(bytes)) + 255) & ~((size_t)255);

extern "C" void kernel_launch(void* const* d_in, const int* in_sizes, int n_in,
                              void* d_out, int out_size, void* d_ws, size_t ws_size,
                              hipStream_t stream)
{
    const float* x  = (const float*)d_in[0];
    const float* a  = (const float*)d_in[1];
    const float* W1 = (const float*)d_in[2];
    const float* W2 = (const float*)d_in[3];
    const float* W3 = (const float*)d_in[4];
    const float* W4 = (const float*)d_in[5];
    const float* s1 = (const float*)d_in[6];
    const float* s2 = (const float*)d_in[7];
    float* out = (float*)d_out;
    (void)in_sizes; (void)n_in; (void)out_size; (void)ws_size;

    char* wp = (char*)d_ws;
    CARVE(u16*,   ellA,  (size_t)NNODES * STRA * sizeof(u16));   // 5.2 MB
    CARVE(int*,   cntA,  NNODES * sizeof(int));
    CARVE(int*,   diagA, NNODES * sizeof(int));
    CARVE(float*, dnA,   NNODES * sizeof(float));
    CARVE(float*, Z1,    (size_t)NNODES * FH * sizeof(float));
    CARVE(float*, X1,    (size_t)NNODES * FH * sizeof(float));
    CARVE(float*, sc1,   NNODES * sizeof(float));
    CARVE(int*,   rank1, NNODES * sizeof(int));
    CARVE(int*,   idx1,  NNODES * sizeof(int));
    CARVE(u16*,   ellS,  (size_t)KP1 * STRS * sizeof(u16));      // 2.6 MB
    CARVE(int*,   cntS,  KP1 * sizeof(int));
    CARVE(int*,   diagS, KP1 * sizeof(int));
    CARVE(float*, dnS,   KP1 * sizeof(float));
    CARVE(float*, Z2f,   (size_t)NNODES * FH * sizeof(float));   // X1@W2 over ALL rows
    CARVE(float*, X2,    (size_t)KP1 * FH * sizeof(float));
    CARVE(float*, sc2,   KP1 * sizeof(float));
    CARVE(int*,   rank2, KP1 * sizeof(int));
    CARVE(int*,   idx2,  KP1 * sizeof(int));
    CARVE(float*, Z3f,   (size_t)KP1 * FH * sizeof(float));      // X2@W3 over all pooled rows
    CARVE(float*, Z4r,   (size_t)KP1 * COUT * sizeof(float));    // rank-space X3@W4
    CARVE(u32*,   barws, 64 * sizeof(u32));                      // grid barrier state

    // 1) one full 256MB pass -> ELL + co-launched Z1 = x@W1 + barrier init
    build_ell<<<NNODES + (NNODES * FH) / 256, 256, 0, stream>>>(
        a, NNODES, STRA, ellA, cntA, diagA, dnA, x, W1, Z1, FIN, barws);

    // 2) cooperative grid size: query once, clamp to validated co-residency
    static int g_cgrid = 0;
    if (g_cgrid == 0) {
        int maxb = 0;
        if (hipOccupancyMaxActiveBlocksPerMultiprocessor(&maxb, (const void*)gcn_pipeline, 256, 0)
                != hipSuccess || maxb <= 0)
            maxb = 2;  // conservative
        int ncu = 256;
        hipDeviceProp_t props;
        if (hipGetDeviceProperties(&props, 0) == hipSuccess && props.multiProcessorCount > 0)
            ncu = props.multiProcessorCount;
        long g = (long)maxb * (long)ncu;
        if (g > CGRID_MAX) g = CGRID_MAX;
        if (g < 2) g = 2;
        g_cgrid = (int)g;
    }

    GcnP pp;
    pp.ellA = ellA; pp.cntA = cntA; pp.diagA = diagA; pp.dnA = dnA;
    pp.Z1 = Z1; pp.X1 = X1; pp.sc1 = sc1; pp.rank1 = rank1; pp.idx1 = idx1;
    pp.ellS = ellS; pp.cntS = cntS; pp.diagS = diagS; pp.dnS = dnS;
    pp.Z2f = Z2f; pp.X2 = X2; pp.sc2 = sc2; pp.rank2 = rank2; pp.idx2 = idx2;
    pp.Z3f = Z3f; pp.Z4r = Z4r;
    pp.W2 = W2; pp.W3 = W3; pp.W4 = W4; pp.s1 = s1; pp.s2 = s2;
    pp.out = out;
    pp.bar = barws;
    void* kargs[] = { (void*)&pp };
    hipError_t ce = hipLaunchCooperativeKernel((const void*)gcn_pipeline,
                                               dim3((unsigned)g_cgrid), dim3(256), kargs, 0u, stream);
    if (ce != hipSuccess) {
        // Fallback: proven multi-kernel pipeline (round-0 structure)
        k_spmm<<<NNODES / 4, 256, 0, stream>>>(ellA, cntA, diagA, dnA, Z1,
            (const int*)0, (const int*)0, X1, sc1, s1, (const float*)0, (float*)0, NNODES, STRA, 0);
        k_topk_gemm<<<1 + (NNODES * FH) / 256, 256, 0, stream>>>(
            sc1, NNODES, KP1, rank1, idx1, X1, W2, Z2f, FH);
        k_subell<<<KP1 / 4, 256, 0, stream>>>(ellA, cntA, diagA, idx1, rank1,
            ellS, cntS, diagS, dnS, KP1, STRA, STRS);
        k_spmm<<<KP1 / 4, 256, 0, stream>>>(ellS, cntS, diagS, dnS, Z2f,
            idx1, (const int*)0, X2, sc2, s2, (const float*)0, (float*)0, KP1, STRS, 1);
        k_topk_gemm<<<1 + (KP1 * FH) / 256, 256, 0, stream>>>(
            sc2, KP1, KP2, rank2, idx2, X2, W3, Z3f, FH);
        k_spmm<<<KP1 / 4, 256, 0, stream>>>(ellS, cntS, diagS, dnS, Z3f,
            (const int*)0, rank2, (float*)0, (float*)0, (const float*)0, W4, Z4r, KP1, STRS, 2);
        k_spmmout<<<NNODES / 4, 256, 0, stream>>>(ellA, cntA, diagA, dnA, Z4r, rank1, out, NNODES, STRA);
    }
}

// Round 4
// 625.029 us; speedup vs baseline: 1.3695x; 1.0685x over previous
//
#include <hip/hip_runtime.h>
#include <stdint.h>

#define NNODES 8192
#define KP1 4096
#define KP2 2048
#define FIN 16
#define FH 32
#define COUT 2
#define STRA 320   // max off-diag nnz/row; mean ~163, sigma ~12.6 -> >12 sigma headroom
#define STRS 320
#define CGRID_MAX 1024
#define GRPSH 5
#define GRPSZ 32
#define BARWORDS (66 * 32)   // 32 grp_cnt lines + 32 grp_gen lines + root_cnt + root_gen

typedef unsigned short u16;
typedef unsigned int u32;

// ---------------------------------------------------------------------------
// Kernel 1: blocks [0,n) stream the 256MB dense adjacency ONCE (float4,
// coalesced, block-local LDS counting) -> u16 ELL; blocks [n,...) compute
// Z1 = x @ W1. Block n additionally zero-inits the grid-barrier state with
// agent-scope atomic stores (LLC-visible to the pipeline's atomics).
// ---------------------------------------------------------------------------
__global__ __launch_bounds__(256) void build_ell(const float* __restrict__ A, int n, int stride,
        u16* __restrict__ ell, int* __restrict__ rowcnt, int* __restrict__ diag, float* __restrict__ dnorm,
        const float* __restrict__ Xf, const float* __restrict__ Wf, float* __restrict__ Zf, int kf,
        u32* __restrict__ bar)
{
    if ((int)blockIdx.x >= n) {
        if ((int)blockIdx.x == n) {
            for (int w = threadIdx.x; w < BARWORDS; w += 256)
                __hip_atomic_store(&bar[w], 0u, __ATOMIC_RELAXED, __HIP_MEMORY_SCOPE_AGENT);
        }
        int t = ((int)blockIdx.x - n) * 256 + threadIdx.x;
        int i = t >> 5;
        int f = t & 31;
        const float* xr = Xf + (size_t)i * kf;
        float acc = 0.0f;
        for (int k = 0; k < kf; ++k) acc += xr[k] * Wf[k * 32 + f];
        Zf[t] = acc;
        return;
    }
    __shared__ int cnt;
    __shared__ int dg;
    int row = blockIdx.x;
    if (threadIdx.x == 0) { cnt = 0; dg = 0; }
    __syncthreads();
    const float4* arow4 = (const float4*)(A + (size_t)row * n);
    u16* erow = ell + (size_t)row * stride;
    int n4 = n >> 2;
    for (int c4 = threadIdx.x; c4 < n4; c4 += 256) {
        float4 v = arow4[c4];
        if (v.x == 0.0f && v.y == 0.0f && v.z == 0.0f && v.w == 0.0f) continue;
        int cb = c4 << 2;
        if (v.x != 0.0f) {
            if (cb == row) dg = 1;
            else { int p = atomicAdd(&cnt, 1); if (p < stride) erow[p] = (u16)cb; }
        }
        if (v.y != 0.0f) {
            int c = cb + 1;
            if (c == row) dg = 1;
            else { int p = atomicAdd(&cnt, 1); if (p < stride) erow[p] = (u16)c; }
        }
        if (v.z != 0.0f) {
            int c = cb + 2;
            if (c == row) dg = 1;
            else { int p = atomicAdd(&cnt, 1); if (p < stride) erow[p] = (u16)c; }
        }
        if (v.w != 0.0f) {
            int c = cb + 3;
            if (c == row) dg = 1;
            else { int p = atomicAdd(&cnt, 1); if (p < stride) erow[p] = (u16)c; }
        }
    }
    __syncthreads();
    if (threadIdx.x == 0) {
        int cf = cnt;
        rowcnt[row] = cf < stride ? cf : stride;
        diag[row] = dg;
        dnorm[row] = rsqrtf((float)(cf + dg + 1) + 1e-10f);
    }
}

// ---------------------------------------------------------------------------
// Hierarchical grid barrier (32 blocks/group). r3 measured ~57us/barrier with
// a FLAT barrier: 1023 pollers on ONE LLC line saturate the bank queue.
// Here: arrivals on 32 distinct lines; 32 leader-RMWs on root; leaders poll
// root_gen (32 pollers); members poll their group's gen line (<=31 pollers).
// Polls are agent-scope relaxed atomic loads (bypass stale per-XCD L2) with
// s_sleep backoff. __threadfence release/acquire handles data visibility.
// ---------------------------------------------------------------------------
__device__ __forceinline__ void gbar(u32* bar, int bid, int nblk)
{
    __syncthreads();
    if (threadIdx.x == 0) {
        __threadfence();   // release: prior global writes visible device-wide
        int g = bid >> GRPSH;
        int ngrp = (nblk + GRPSZ - 1) >> GRPSH;
        int gsz = nblk - (g << GRPSH); if (gsz > GRPSZ) gsz = GRPSZ;
        u32* gcnt = bar + (size_t)g * 32;
        u32* ggen = bar + (size_t)(32 + g) * 32;
        u32* rcnt = bar + (size_t)64 * 32;
        u32* rgen = bar + (size_t)65 * 32;
        u32 sg = __hip_atomic_load(ggen, __ATOMIC_RELAXED, __HIP_MEMORY_SCOPE_AGENT);
        u32 a = __hip_atomic_fetch_add(gcnt, 1u, __ATOMIC_RELAXED, __HIP_MEMORY_SCOPE_AGENT);
        if (a == (u32)(gsz - 1)) {          // last arriver in group -> leader
            u32 sr = __hip_atomic_load(rgen, __ATOMIC_RELAXED, __HIP_MEMORY_SCOPE_AGENT);
            u32 r = __hip_atomic_fetch_add(rcnt, 1u, __ATOMIC_RELAXED, __HIP_MEMORY_SCOPE_AGENT);
            if (r == (u32)(ngrp - 1)) {     // last group -> release root
                __hip_atomic_store(rcnt, 0u, __ATOMIC_RELAXED, __HIP_MEMORY_SCOPE_AGENT);
                __hip_atomic_fetch_add(rgen, 1u, __ATOMIC_RELEASE, __HIP_MEMORY_SCOPE_AGENT);
            } else {
                while (__hip_atomic_load(rgen, __ATOMIC_RELAXED, __HIP_MEMORY_SCOPE_AGENT) == sr)
                    __builtin_amdgcn_s_sleep(8);
            }
            __hip_atomic_store(gcnt, 0u, __ATOMIC_RELAXED, __HIP_MEMORY_SCOPE_AGENT);
            __hip_atomic_fetch_add(ggen, 1u, __ATOMIC_RELEASE, __HIP_MEMORY_SCOPE_AGENT);
        } else {
            while (__hip_atomic_load(ggen, __ATOMIC_RELAXED, __HIP_MEMORY_SCOPE_AGENT) == sg)
                __builtin_amdgcn_s_sleep(8);
        }
        __threadfence();   // acquire: see other blocks' writes
    }
    __syncthreads();
}

// ---------------------------------------------------------------------------
// Shared phase bodies (used by the cooperative pipeline AND the fallback path)
// ---------------------------------------------------------------------------
struct TkS {
    u32 hist[4][256];
    u32 wsum[4];
    u32 pref;
    u32 rem;
};  // 4,120 B

__device__ __forceinline__ u32 km_of(float f)
{
    u32 u = __float_as_uint(f);
    u32 m;
    if (u & 0x80000000u) m = ~u; else m = u | 0x80000000u;  // monotone asc in float
    return ~m;                                              // asc in km == desc in score
}

// Exact top-K (jax.lax.top_k set semantics: value desc, index-asc ties).
// Block-local: call from exactly one block (256 threads).
__device__ void topk_block0(TkS& s, const float* __restrict__ scores, int n, int K,
                            int* __restrict__ rank, int* __restrict__ idxlist, int tid)
{
    int wv = tid >> 6;
    int lane = tid & 63;
    int per = n >> 8;       // 32 (n=8192) or 16 (n=4096)
    int base = tid * per;
    if (tid == 0) { s.pref = 0u; s.rem = (u32)K; }
    __syncthreads();
    for (int bp = 3; bp >= 0; --bp) {
        s.hist[0][tid] = 0u;
        s.hist[1][tid] = 0u;
        s.hist[2][tid] = 0u;
        s.hist[3][tid] = 0u;
        __syncthreads();                 // hist zeroed; prev-iter pref visible
        u32 maskhi = 0u;
        if (bp < 3) maskhi = 0xFFFFFFFFu << ((bp + 1) * 8);
        u32 pref = s.pref;
        u32 rem = s.rem;
        for (int e = 0; e < per; ++e) {
            u32 km = km_of(scores[base + e]);
            if ((km & maskhi) == pref) atomicAdd(&s.hist[wv][(km >> (bp * 8)) & 255u], 1u);
        }
        __syncthreads();                 // atomics done
        u32 tot = s.hist[0][tid] + s.hist[1][tid] + s.hist[2][tid] + s.hist[3][tid];
        u32 vv = tot;
        u32 t2;
        t2 = __shfl(vv, lane - 1);  if (lane >= 1)  vv += t2;
        t2 = __shfl(vv, lane - 2);  if (lane >= 2)  vv += t2;
        t2 = __shfl(vv, lane - 4);  if (lane >= 4)  vv += t2;
        t2 = __shfl(vv, lane - 8);  if (lane >= 8)  vv += t2;
        t2 = __shfl(vv, lane - 16); if (lane >= 16) vv += t2;
        t2 = __shfl(vv, lane - 32); if (lane >= 32) vv += t2;
        if (lane == 63) s.wsum[wv] = vv;
        __syncthreads();                 // wave sums visible
        u32 add = 0u;
        if (wv > 0) add += s.wsum[0];
        if (wv > 1) add += s.wsum[1];
        if (wv > 2) add += s.wsum[2];
        u32 cum = vv + add;
        if (tot != 0u && cum >= rem && cum - tot < rem) {  // unique boundary bin
            s.pref = pref | ((u32)tid << (bp * 8));
            s.rem = rem - (cum - tot);
        }
    }
    __syncthreads();
    u32 T = s.pref;        // K-th smallest km
    u32 need_eq = s.rem;   // how many km==T to take (lowest node index first)
    u32 run = 0u;          // high16 = #(km<T), low16 = #(km==T)
    for (int e = 0; e < per; ++e) {
        u32 km = km_of(scores[base + e]);
        if (km < T) run += 0x10000u;
        else if (km == T) run += 1u;
    }
    u32 v2 = run;
    u32 t3;
    t3 = __shfl(v2, lane - 1);  if (lane >= 1)  v2 += t3;
    t3 = __shfl(v2, lane - 2);  if (lane >= 2)  v2 += t3;
    t3 = __shfl(v2, lane - 4);  if (lane >= 4)  v2 += t3;
    t3 = __shfl(v2, lane - 8);  if (lane >= 8)  v2 += t3;
    t3 = __shfl(v2, lane - 16); if (lane >= 16) v2 += t3;
    t3 = __shfl(v2, lane - 32); if (lane >= 32) v2 += t3;
    if (lane == 63) s.wsum[wv] = v2;
    __syncthreads();
    u32 add2 = 0u;
    if (wv > 0) add2 += s.wsum[0];
    if (wv > 1) add2 += s.wsum[1];
    if (wv > 2) add2 += s.wsum[2];
    u32 cur = v2 + add2 - run;   // exclusive prefix for this thread's chunk
    for (int e = 0; e < per; ++e) {
        int v = base + e;
        u32 km = km_of(scores[v]);
        u32 ltb = cur >> 16;
        u32 eqb = cur & 0xFFFFu;
        u32 eqs = eqb < need_eq ? eqb : need_eq;
        int sel = 0;
        if (km < T) { sel = 1; cur += 0x10000u; }
        else if (km == T) { if (eqb < need_eq) sel = 1; cur += 1u; }
        if (sel) {
            int r = (int)(ltb + eqs);
            rank[v] = r;
            idxlist[r] = v;
        } else {
            rank[v] = -1;
        }
    }
}

// SpMM (F=32) + relu; one wave per row, 8 lanes per neighbor, float4 per lane.
// EPI: fused in-register row@Wn (32x32) epilogue -> Zn[wid] (removes the
//      separate dense-GEMM phase AND the X1/X2 intermediate buffers).
// FW4: fused row@Wn (32x2) epilogue -> ((float2*)Zn)[wid].
// SC : scores[wid] = relu_row @ svec.
template<bool REMAP, bool MASK, bool FW4, bool SC, bool EPI>
__device__ __forceinline__ void spmm_phase(
        const u16* __restrict__ ell, const int* __restrict__ rowcnt,
        const int* __restrict__ diag, const float* __restrict__ dnorm,
        const float* __restrict__ Z, const int* __restrict__ remap, const int* __restrict__ maskp,
        float* __restrict__ scores, const float* __restrict__ svec,
        const float* __restrict__ Wn, float* __restrict__ Zn,
        int n, int stride, int gwave, int nwaves, int lane)
{
    int g = lane >> 3;   // neighbor sub-slot 0..7
    int q = lane & 7;    // feature quad 0..7
    for (int wid = gwave; wid < n; wid += nwaves) {
        int cnt = rowcnt[wid];
        const u16* erow = ell + (size_t)wid * stride;
        float ax = 0.0f, ay = 0.0f, az = 0.0f, aw = 0.0f;
        for (int it = g; it < cnt; it += 8) {
            int c = erow[it];
            if (MASK && maskp[c] < 0) continue;
            int zc = REMAP ? remap[c] : c;
            float dn = dnorm[c];
            const float4* zp = (const float4*)(Z + (size_t)zc * 32);
            float4 zv = zp[q];
            ax += dn * zv.x;
            ay += dn * zv.y;
            az += dn * zv.z;
            aw += dn * zv.w;
        }
        ax += __shfl_xor(ax, 8);  ay += __shfl_xor(ay, 8);
        az += __shfl_xor(az, 8);  aw += __shfl_xor(aw, 8);
        ax += __shfl_xor(ax, 16); ay += __shfl_xor(ay, 16);
        az += __shfl_xor(az, 16); aw += __shfl_xor(aw, 16);
        ax += __shfl_xor(ax, 32); ay += __shfl_xor(ay, 32);
        az += __shfl_xor(az, 32); aw += __shfl_xor(aw, 32);
        float ox = 0.0f, oy = 0.0f, oz = 0.0f, ow = 0.0f;
        if (g == 0) {   // lanes 0..7 hold the full sum for feature quad q
            float dr = dnorm[wid];
            bool selfok = !(MASK && maskp[wid] < 0);
            if (selfok) {
                int zc = REMAP ? remap[wid] : wid;
                const float4* zp = (const float4*)(Z + (size_t)zc * 32);
                float4 zv = zp[q];
                float cf = (float)(diag[wid] + 1) * dr;
                ax += cf * zv.x;
                ay += cf * zv.y;
                az += cf * zv.z;
                aw += cf * zv.w;
            }
            ox = fmaxf(dr * ax, 0.0f);
            oy = fmaxf(dr * ay, 0.0f);
            oz = fmaxf(dr * az, 0.0f);
            ow = fmaxf(dr * aw, 0.0f);
            if (FW4) {
                // fused (32x2) GEMM: row @ W4 -> 2 outputs; reduce over 8 q-lanes
                int kb = q * 4;
                float p0 = ox * Wn[(kb + 0) * 2 + 0] + oy * Wn[(kb + 1) * 2 + 0]
                         + oz * Wn[(kb + 2) * 2 + 0] + ow * Wn[(kb + 3) * 2 + 0];
                float p1 = ox * Wn[(kb + 0) * 2 + 1] + oy * Wn[(kb + 1) * 2 + 1]
                         + oz * Wn[(kb + 2) * 2 + 1] + ow * Wn[(kb + 3) * 2 + 1];
                p0 += __shfl_xor(p0, 1);
                p1 += __shfl_xor(p1, 1);
                p0 += __shfl_xor(p0, 2);
                p1 += __shfl_xor(p1, 2);
                p0 += __shfl_xor(p0, 4);
                p1 += __shfl_xor(p1, 4);
                if (q == 0) {
                    float2 r;
                    r.x = p0;
                    r.y = p1;
                    ((float2*)Zn)[wid] = r;
                }
            } else if (SC) {
                const float4* sp = (const float4*)svec;
                float4 sv = sp[q];
                float pp = ox * sv.x + oy * sv.y + oz * sv.z + ow * sv.w;
                pp += __shfl_xor(pp, 1);
                pp += __shfl_xor(pp, 2);
                pp += __shfl_xor(pp, 4);
                if (q == 0) scores[wid] = pp;
            }
        }
        if (EPI) {
            // in-register row @ Wn (32x32): broadcast row[k] from lane k>>2
            // (component k&3 of its float4), every lane accumulates one column.
            int f = lane & 31;
            float acc = 0.0f;
#pragma unroll
            for (int k = 0; k < 32; ++k) {
                float comp = ((k & 3) == 0) ? ox : ((k & 3) == 1) ? oy
                           : ((k & 3) == 2) ? oz : ow;
                float rowk = __shfl(comp, k >> 2);
                acc += rowk * Wn[k * 32 + f];
            }
            if (lane < 32) Zn[(size_t)wid * 32 + f] = acc;
        }
    }
}

// Subgraph ELL for A1p = a[idx1][:,idx1]; wave-compaction via ballot.
__device__ __forceinline__ void subell_phase(const u16* __restrict__ ellA, const int* __restrict__ rowcntA,
        const int* __restrict__ diagA, const int* __restrict__ idx1, const int* __restrict__ rank1,
        u16* __restrict__ ellS, int* __restrict__ rowcntS, int* __restrict__ diagS, float* __restrict__ dnormS,
        int k1, int strideA, int strideS, int gwave, int nwaves, int lane)
{
    for (int wid = gwave; wid < k1; wid += nwaves) {
        int r = idx1[wid];
        int cnt = rowcntA[r];
        const u16* erow = ellA + (size_t)r * strideA;
        u16* srow = ellS + (size_t)wid * strideS;
        int outn = 0;
        for (int t0 = 0; t0 < cnt; t0 += 64) {
            int it = t0 + lane;
            int rk = -1;
            if (it < cnt) rk = rank1[erow[it]];
            unsigned long long b = __ballot(rk >= 0);
            int ofs = __popcll(b & ((1ull << lane) - 1ull));
            if (rk >= 0) srow[outn + ofs] = (u16)rk;
            outn += __popcll(b);
        }
        if (lane == 0) {
            int dg = diagA[r];
            rowcntS[wid] = outn;
            diagS[wid] = dg;
            dnormS[wid] = rsqrtf((float)(outn + dg + 1) + 1e-10f);
        }
    }
}

// Final SpMM (F=2) + 2-way softmax; unpool1 folded into the gat[] gather.
__device__ __forceinline__ void spmmout_phase(const u16* __restrict__ ell, const int* __restrict__ rowcnt,
        const int* __restrict__ diag, const float* __restrict__ dnorm, const float* __restrict__ Zr,
        const int* __restrict__ gat, float* __restrict__ out, int n, int stride,
        int gwave, int nwaves, int lane)
{
    const float2* Z2 = (const float2*)Zr;
    for (int wid = gwave; wid < n; wid += nwaves) {
        int cnt = rowcnt[wid];
        const u16* erow = ell + (size_t)wid * stride;
        float ax = 0.0f, ay = 0.0f;
        for (int it = lane; it < cnt; it += 64) {
            int c = erow[it];
            int rk = gat[c];
            if (rk >= 0) {
                float dn = dnorm[c];
                float2 zv = Z2[rk];
                ax += dn * zv.x;
                ay += dn * zv.y;
            }
        }
        ax += __shfl_xor(ax, 1);  ay += __shfl_xor(ay, 1);
        ax += __shfl_xor(ax, 2);  ay += __shfl_xor(ay, 2);
        ax += __shfl_xor(ax, 4);  ay += __shfl_xor(ay, 4);
        ax += __shfl_xor(ax, 8);  ay += __shfl_xor(ay, 8);
        ax += __shfl_xor(ax, 16); ay += __shfl_xor(ay, 16);
        ax += __shfl_xor(ax, 32); ay += __shfl_xor(ay, 32);
        if (lane == 0) {
            float dr = dnorm[wid];
            int rks = gat[wid];
            if (rks >= 0) {
                float cf = (float)(diag[wid] + 1) * dr;
                float2 zs = Z2[rks];
                ax += cf * zs.x;
                ay += cf * zs.y;
            }
            float v0 = dr * ax;
            float v1 = dr * ay;
            float m = fmaxf(v0, v1);
            float e0 = __expf(v0 - m);
            float e1 = __expf(v1 - m);
            float inv = 1.0f / (e0 + e1);
            float2 r;
            r.x = e0 * inv;
            r.y = e1 * inv;
            ((float2*)out)[wid] = r;
        }
    }
}

struct GcnP {
    const u16* ellA; const int* cntA; const int* diagA; const float* dnA;
    const float* Z1; float* sc1; int* rank1; int* idx1;
    u16* ellS; int* cntS; int* diagS; float* dnS;
    float* Z2f; float* sc2; int* rank2; int* idx2;
    float* Z3f; float* Z4r;
    const float* W2; const float* W3; const float* W4; const float* s1; const float* s2;
    float* out;
    u32* bar;
};

// ---------------------------------------------------------------------------
// Cooperative pipeline: everything after the A-scan; hierarchical gbar
// between phases (flat gbar measured ~57us/sync at 1024 blocks — r3).
// ---------------------------------------------------------------------------
__global__ __launch_bounds__(256, 4) void gcn_pipeline(GcnP p)
{
    __shared__ TkS sm;
    int tid = threadIdx.x;
    int bid = blockIdx.x;
    int lane = tid & 63;
    int gwave = (bid * 256 + tid) >> 6;
    int nwaves = ((int)gridDim.x * 256) >> 6;
    int nblk = (int)gridDim.x;

    // P1: GCN1 spmm + pool1 scores + fused Z2f = X1@W2 (all rows)
    spmm_phase<false, false, false, true, true>(p.ellA, p.cntA, p.diagA, p.dnA, p.Z1,
        (const int*)0, (const int*)0, p.sc1, p.s1, p.W2, p.Z2f,
        NNODES, STRA, gwave, nwaves, lane);
    gbar(p.bar, bid, nblk);

    // P2: pool1 top-k (block 0; other blocks' barrier entry overlaps it)
    if (bid == 0) topk_block0(sm, p.sc1, NNODES, KP1, p.rank1, p.idx1, tid);
    gbar(p.bar, bid, nblk);

    // P3: subgraph ELL
    subell_phase(p.ellA, p.cntA, p.diagA, p.idx1, p.rank1, p.ellS, p.cntS, p.diagS, p.dnS,
        KP1, STRA, STRS, gwave, nwaves, lane);
    gbar(p.bar, bid, nblk);

    // P4: GCN2 on subgraph (Z gathered via idx1) + fused Z3f = X2@W3
    spmm_phase<true, false, false, true, true>(p.ellS, p.cntS, p.diagS, p.dnS, p.Z2f,
        p.idx1, (const int*)0, p.sc2, p.s2, p.W3, p.Z3f,
        KP1, STRS, gwave, nwaves, lane);
    gbar(p.bar, bid, nblk);

    // P5: pool2 top-k (block 0)
    if (bid == 0) topk_block0(sm, p.sc2, KP1, KP2, p.rank2, p.idx2, tid);
    gbar(p.bar, bid, nblk);

    // P6: GCN3 with pool2 mask + fused W4 epilogue -> Z4r
    spmm_phase<false, true, true, false, false>(p.ellS, p.cntS, p.diagS, p.dnS, p.Z3f,
        (const int*)0, p.rank2, (float*)0, (const float*)0, p.W4, p.Z4r,
        KP1, STRS, gwave, nwaves, lane);
    gbar(p.bar, bid, nblk);

    // P7: GCN4 + softmax (unpool1 folded into rank1 gather)
    spmmout_phase(p.ellA, p.cntA, p.diagA, p.dnA, p.Z4r, p.rank1, p.out,
        NNODES, STRA, gwave, nwaves, lane);
}

// ---------------------------------------------------------------------------
// Fallback path: separate kernels, used only if the cooperative launch is
// rejected at enqueue time.
// ---------------------------------------------------------------------------
__global__ __launch_bounds__(256) void k_spmm(const u16* __restrict__ ell, const int* __restrict__ rowcnt,
        const int* __restrict__ diag, const float* __restrict__ dnorm, const float* __restrict__ Z,
        const int* __restrict__ remap, const int* __restrict__ maskp,
        float* __restrict__ scores, const float* __restrict__ svec,
        const float* __restrict__ Wn, float* __restrict__ Zn, int n, int stride, int mode)
{
    int gwave = ((int)blockIdx.x * 256 + (int)threadIdx.x) >> 6;
    int nwaves = ((int)gridDim.x * 256) >> 6;
    int lane = threadIdx.x & 63;
    if (mode == 0)
        spmm_phase<false, false, false, true, true>(ell, rowcnt, diag, dnorm, Z, remap, maskp,
            scores, svec, Wn, Zn, n, stride, gwave, nwaves, lane);
    else if (mode == 1)
        spmm_phase<true, false, false, true, true>(ell, rowcnt, diag, dnorm, Z, remap, maskp,
            scores, svec, Wn, Zn, n, stride, gwave, nwaves, lane);
    else
        spmm_phase<false, true, true, false, false>(ell, rowcnt, diag, dnorm, Z, remap, maskp,
            scores, svec, Wn, Zn, n, stride, gwave, nwaves, lane);
}

__global__ __launch_bounds__(256) void k_topk(const float* __restrict__ scores, int n, int K,
        int* __restrict__ rank, int* __restrict__ idxlist)
{
    __shared__ TkS sm;
    if (blockIdx.x == 0) topk_block0(sm, scores, n, K, rank, idxlist, threadIdx.x);
}

__global__ __launch_bounds__(256) void k_subell(const u16* __restrict__ ellA, const int* __restrict__ rowcntA,
        const int* __restrict__ diagA, const int* __restrict__ idx1, const int* __restrict__ rank1,
        u16* __restrict__ ellS, int* __restrict__ rowcntS, int* __restrict__ diagS, float* __restrict__ dnormS,
        int k1, int strideA, int strideS)
{
    int gwave = ((int)blockIdx.x * 256 + (int)threadIdx.x) >> 6;
    int nwaves = ((int)gridDim.x * 256) >> 6;
    subell_phase(ellA, rowcntA, diagA, idx1, rank1, ellS, rowcntS, diagS, dnormS,
        k1, strideA, strideS, gwave, nwaves, threadIdx.x & 63);
}

__global__ __launch_bounds__(256) void k_spmmout(const u16* __restrict__ ell, const int* __restrict__ rowcnt,
        const int* __restrict__ diag, const float* __restrict__ dnorm, const float* __restrict__ Zr,
        const int* __restrict__ gat, float* __restrict__ out, int n, int stride)
{
    int gwave = ((int)blockIdx.x * 256 + (int)threadIdx.x) >> 6;
    int nwaves = ((int)gridDim.x * 256) >> 6;
    spmmout_phase(ell, rowcnt, diag, dnorm, Zr, gat, out, n, stride, gwave, nwaves, threadIdx.x & 63);
}

#define CARVE(type, name, bytes) \
    type name = (type)wp; wp += (((size_t)(bytes)) + 255) & ~((size_t)255);

extern "C" void kernel_launch(void* const* d_in, const int* in_sizes, int n_in,
                              void* d_out, int out_size, void* d_ws, size_t ws_size,
                              hipStream_t stream)
{
    const float* x  = (const float*)d_in[0];
    const float* a  = (const float*)d_in[1];
    const float* W1 = (const float*)d_in[2];
    const float* W2 = (const float*)d_in[3];
    const float* W3 = (const float*)d_in[4];
    const float* W4 = (const float*)d_in[5];
    const float* s1 = (const float*)d_in[6];
    const float* s2 = (const float*)d_in[7];
    float* out = (float*)d_out;
    (void)in_sizes; (void)n_in; (void)out_size; (void)ws_size;

    char* wp = (char*)d_ws;
    CARVE(u16*,   ellA,  (size_t)NNODES * STRA * sizeof(u16));   // 5.2 MB
    CARVE(int*,   cntA,  NNODES * sizeof(int));
    CARVE(int*,   diagA, NNODES * sizeof(int));
    CARVE(float*, dnA,   NNODES * sizeof(float));
    CARVE(float*, Z1,    (size_t)NNODES * FH * sizeof(float));
    CARVE(float*, sc1,   NNODES * sizeof(float));
    CARVE(int*,   rank1, NNODES * sizeof(int));
    CARVE(int*,   idx1,  NNODES * sizeof(int));
    CARVE(u16*,   ellS,  (size_t)KP1 * STRS * sizeof(u16));      // 2.6 MB
    CARVE(int*,   cntS,  KP1 * sizeof(int));
    CARVE(int*,   diagS, KP1 * sizeof(int));
    CARVE(float*, dnS,   KP1 * sizeof(float));
    CARVE(float*, Z2f,   (size_t)NNODES * FH * sizeof(float));   // X1@W2 over ALL rows
    CARVE(float*, sc2,   KP1 * sizeof(float));
    CARVE(int*,   rank2, KP1 * sizeof(int));
    CARVE(int*,   idx2,  KP1 * sizeof(int));
    CARVE(float*, Z3f,   (size_t)KP1 * FH * sizeof(float));      // X2@W3 over all pooled rows
    CARVE(float*, Z4r,   (size_t)KP1 * COUT * sizeof(float));    // rank-space X3@W4
    CARVE(u32*,   barws, BARWORDS * sizeof(u32));                // hierarchical barrier state

    // 1) one full 256MB pass -> ELL + co-launched Z1 = x@W1 + barrier init
    build_ell<<<NNODES + (NNODES * FH) / 256, 256, 0, stream>>>(
        a, NNODES, STRA, ellA, cntA, diagA, dnA, x, W1, Z1, FIN, barws);

    // 2) cooperative grid size: query once, clamp to validated co-residency
    static int g_cgrid = 0;
    if (g_cgrid == 0) {
        int maxb = 0;
        if (hipOccupancyMaxActiveBlocksPerMultiprocessor(&maxb, (const void*)gcn_pipeline, 256, 0)
                != hipSuccess || maxb <= 0)
            maxb = 2;  // conservative
        int ncu = 256;
        hipDeviceProp_t props;
        if (hipGetDeviceProperties(&props, 0) == hipSuccess && props.multiProcessorCount > 0)
            ncu = props.multiProcessorCount;
        long g = (long)maxb * (long)ncu;
        if (g > CGRID_MAX) g = CGRID_MAX;
        if (g < 2) g = 2;
        g_cgrid = (int)g;
    }

    GcnP pp;
    pp.ellA = ellA; pp.cntA = cntA; pp.diagA = diagA; pp.dnA = dnA;
    pp.Z1 = Z1; pp.sc1 = sc1; pp.rank1 = rank1; pp.idx1 = idx1;
    pp.ellS = ellS; pp.cntS = cntS; pp.diagS = diagS; pp.dnS = dnS;
    pp.Z2f = Z2f; pp.sc2 = sc2; pp.rank2 = rank2; pp.idx2 = idx2;
    pp.Z3f = Z3f; pp.Z4r = Z4r;
    pp.W2 = W2; pp.W3 = W3; pp.W4 = W4; pp.s1 = s1; pp.s2 = s2;
    pp.out = out;
    pp.bar = barws;
    void* kargs[] = { (void*)&pp };
    hipError_t ce = hipLaunchCooperativeKernel((const void*)gcn_pipeline,
                                               dim3((unsigned)g_cgrid), dim3(256), kargs, 0u, stream);
    if (ce != hipSuccess) {
        // Fallback: multi-kernel pipeline
        k_spmm<<<NNODES / 4, 256, 0, stream>>>(ellA, cntA, diagA, dnA, Z1,
            (const int*)0, (const int*)0, sc1, s1, W2, Z2f, NNODES, STRA, 0);
        k_topk<<<1, 256, 0, stream>>>(sc1, NNODES, KP1, rank1, idx1);
        k_subell<<<KP1 / 4, 256, 0, stream>>>(ellA, cntA, diagA, idx1, rank1,
            ellS, cntS, diagS, dnS, KP1, STRA, STRS);
        k_spmm<<<KP1 / 4, 256, 0, stream>>>(ellS, cntS, diagS, dnS, Z2f,
            idx1, (const int*)0, sc2, s2, W3, Z3f, KP1, STRS, 1);
        k_topk<<<1, 256, 0, stream>>>(sc2, KP1, KP2, rank2, idx2);
        k_spmm<<<KP1 / 4, 256, 0, stream>>>(ellS, cntS, diagS, dnS, Z3f,
            (const int*)0, rank2, (float*)0, (const float*)0, W4, Z4r, KP1, STRS, 2);
        k_spmmout<<<NNODES / 4, 256, 0, stream>>>(ellA, cntA, diagA, dnA, Z4r, rank1, out, NNODES, STRA);
    }
}

// Round 5
// 498.291 us; speedup vs baseline: 1.7178x; 1.2543x over previous
//
#include <hip/hip_runtime.h>
#include <stdint.h>

#define NNODES 8192
#define KP1 4096
#define KP2 2048
#define FIN 16
#define FH 32
#define COUT 2
#define STRA 320   // max off-diag nnz/row; mean ~163, sigma ~12.6 -> >12 sigma headroom
#define STRS 320
#define CGRID 1024
#define GRPSH 5
#define GRPSZ 32
#define BARWORDS (66 * 32)   // 32 grp_cnt lines + 32 grp_gen lines + root_cnt + root_gen
#define RNONE 0xFFFFu

typedef unsigned short u16;
typedef unsigned int u32;

// ---------------------------------------------------------------------------
// Kernel 1: blocks [0,n) stream the 256MB dense adjacency ONCE (float4,
// coalesced, block-local LDS counting) -> u16 ELL; blocks [n,...) compute
// Z1 = x @ W1. Block n zero-inits the grid-barrier state.
// ---------------------------------------------------------------------------
__global__ __launch_bounds__(256) void build_ell(const float* __restrict__ A, int n, int stride,
        u16* __restrict__ ell, int* __restrict__ rowcnt, int* __restrict__ diag, float* __restrict__ dnorm,
        const float* __restrict__ Xf, const float* __restrict__ Wf, float* __restrict__ Zf, int kf,
        u32* __restrict__ bar)
{
    if ((int)blockIdx.x >= n) {
        if ((int)blockIdx.x == n) {
            for (int w = threadIdx.x; w < BARWORDS; w += 256)
                __hip_atomic_store(&bar[w], 0u, __ATOMIC_RELAXED, __HIP_MEMORY_SCOPE_AGENT);
        }
        int t = ((int)blockIdx.x - n) * 256 + threadIdx.x;
        int i = t >> 5;
        int f = t & 31;
        const float* xr = Xf + (size_t)i * kf;
        float acc = 0.0f;
        for (int k = 0; k < kf; ++k) acc += xr[k] * Wf[k * 32 + f];
        Zf[t] = acc;
        return;
    }
    __shared__ int cnt;
    __shared__ int dg;
    int row = blockIdx.x;
    if (threadIdx.x == 0) { cnt = 0; dg = 0; }
    __syncthreads();
    const float4* arow4 = (const float4*)(A + (size_t)row * n);
    u16* erow = ell + (size_t)row * stride;
    int n4 = n >> 2;
    for (int c4 = threadIdx.x; c4 < n4; c4 += 256) {
        float4 v = arow4[c4];
        if (v.x == 0.0f && v.y == 0.0f && v.z == 0.0f && v.w == 0.0f) continue;
        int cb = c4 << 2;
        if (v.x != 0.0f) {
            if (cb == row) dg = 1;
            else { int p = atomicAdd(&cnt, 1); if (p < stride) erow[p] = (u16)cb; }
        }
        if (v.y != 0.0f) {
            int c = cb + 1;
            if (c == row) dg = 1;
            else { int p = atomicAdd(&cnt, 1); if (p < stride) erow[p] = (u16)c; }
        }
        if (v.z != 0.0f) {
            int c = cb + 2;
            if (c == row) dg = 1;
            else { int p = atomicAdd(&cnt, 1); if (p < stride) erow[p] = (u16)c; }
        }
        if (v.w != 0.0f) {
            int c = cb + 3;
            if (c == row) dg = 1;
            else { int p = atomicAdd(&cnt, 1); if (p < stride) erow[p] = (u16)c; }
        }
    }
    __syncthreads();
    if (threadIdx.x == 0) {
        int cf = cnt;
        rowcnt[row] = cf < stride ? cf : stride;
        diag[row] = dg;
        dnorm[row] = rsqrtf((float)(cf + dg + 1) + 1e-10f);
    }
}

// ---------------------------------------------------------------------------
// Hierarchical grid barrier. r4 lesson: __threadfence() (acq_rel agent) emits
// BOTH buffer_wbl2 sc1 AND buffer_inv sc1 — full per-XCD L2 ops; calling it
// twice per block = 4 L2 ops/block/barrier ~= the 40us floor. Here fences are
// directional: RELEASE (waitcnt+wbl2) before arrival, ACQUIRE (inv) after
// wake — half the cache ops. Protocol RMWs/polls are relaxed agent-scope.
// ---------------------------------------------------------------------------
__device__ __forceinline__ void gbar(u32* bar, int bid, int nblk)
{
    __syncthreads();
    if (threadIdx.x == 0) {
        __builtin_amdgcn_fence(__ATOMIC_RELEASE, "agent");   // waitcnt + buffer_wbl2 sc1
        int g = bid >> GRPSH;
        int ngrp = (nblk + GRPSZ - 1) >> GRPSH;
        int gsz = nblk - (g << GRPSH); if (gsz > GRPSZ) gsz = GRPSZ;
        u32* gcnt = bar + (size_t)g * 32;
        u32* ggen = bar + (size_t)(32 + g) * 32;
        u32* rcnt = bar + (size_t)64 * 32;
        u32* rgen = bar + (size_t)65 * 32;
        u32 sg = __hip_atomic_load(ggen, __ATOMIC_RELAXED, __HIP_MEMORY_SCOPE_AGENT);
        u32 a = __hip_atomic_fetch_add(gcnt, 1u, __ATOMIC_RELAXED, __HIP_MEMORY_SCOPE_AGENT);
        if (a == (u32)(gsz - 1)) {          // last arriver in group -> leader
            u32 sr = __hip_atomic_load(rgen, __ATOMIC_RELAXED, __HIP_MEMORY_SCOPE_AGENT);
            u32 r = __hip_atomic_fetch_add(rcnt, 1u, __ATOMIC_RELAXED, __HIP_MEMORY_SCOPE_AGENT);
            if (r == (u32)(ngrp - 1)) {     // last group -> release root
                __hip_atomic_store(rcnt, 0u, __ATOMIC_RELAXED, __HIP_MEMORY_SCOPE_AGENT);
                __hip_atomic_fetch_add(rgen, 1u, __ATOMIC_RELAXED, __HIP_MEMORY_SCOPE_AGENT);
            } else {
                while (__hip_atomic_load(rgen, __ATOMIC_RELAXED, __HIP_MEMORY_SCOPE_AGENT) == sr)
                    __builtin_amdgcn_s_sleep(2);
            }
            __hip_atomic_store(gcnt, 0u, __ATOMIC_RELAXED, __HIP_MEMORY_SCOPE_AGENT);
            __hip_atomic_fetch_add(ggen, 1u, __ATOMIC_RELAXED, __HIP_MEMORY_SCOPE_AGENT);
        } else {
            while (__hip_atomic_load(ggen, __ATOMIC_RELAXED, __HIP_MEMORY_SCOPE_AGENT) == sg)
                __builtin_amdgcn_s_sleep(4);
        }
        __builtin_amdgcn_fence(__ATOMIC_ACQUIRE, "agent");   // buffer_inv sc1
    }
    __syncthreads();
}

// ---------------------------------------------------------------------------
// Shared phase bodies
// ---------------------------------------------------------------------------
struct TkS {
    u32 hist[4][256];
    u32 wsum[4];
    u32 pref;
    u32 rem;
};  // 4,120 B

__device__ __forceinline__ u32 km_of(float f)
{
    u32 u = __float_as_uint(f);
    u32 m;
    if (u & 0x80000000u) m = ~u; else m = u | 0x80000000u;  // monotone asc in float
    return ~m;                                              // asc in km == desc in score
}

// Exact top-K (jax.lax.top_k set semantics: value desc, index-asc ties).
// Every block runs it redundantly into ITS OWN LDS tables (rank_l u16 with
// 0xFFFF = not selected; idx_l u16) — replaces two grid barriers with ~6us of
// parallel redundant work. If mirror, also write the global int tables.
__device__ void topk_local(TkS& s, u16* rank_l, u16* idx_l,
                           const float* __restrict__ scores, int n, int K, int tid,
                           int* __restrict__ grank, int* __restrict__ gidx, bool mirror)
{
    int wv = tid >> 6;
    int lane = tid & 63;
    int per = n >> 8;       // 32 (n=8192) or 16 (n=4096)
    int base = tid * per;
    if (tid == 0) { s.pref = 0u; s.rem = (u32)K; }
    __syncthreads();
    for (int bp = 3; bp >= 0; --bp) {
        s.hist[0][tid] = 0u;
        s.hist[1][tid] = 0u;
        s.hist[2][tid] = 0u;
        s.hist[3][tid] = 0u;
        __syncthreads();                 // hist zeroed; prev-iter pref visible
        u32 maskhi = 0u;
        if (bp < 3) maskhi = 0xFFFFFFFFu << ((bp + 1) * 8);
        u32 pref = s.pref;
        u32 rem = s.rem;
        for (int e = 0; e < per; ++e) {
            u32 km = km_of(scores[base + e]);
            if ((km & maskhi) == pref) atomicAdd(&s.hist[wv][(km >> (bp * 8)) & 255u], 1u);
        }
        __syncthreads();                 // atomics done
        u32 tot = s.hist[0][tid] + s.hist[1][tid] + s.hist[2][tid] + s.hist[3][tid];
        u32 vv = tot;
        u32 t2;
        t2 = __shfl(vv, lane - 1);  if (lane >= 1)  vv += t2;
        t2 = __shfl(vv, lane - 2);  if (lane >= 2)  vv += t2;
        t2 = __shfl(vv, lane - 4);  if (lane >= 4)  vv += t2;
        t2 = __shfl(vv, lane - 8);  if (lane >= 8)  vv += t2;
        t2 = __shfl(vv, lane - 16); if (lane >= 16) vv += t2;
        t2 = __shfl(vv, lane - 32); if (lane >= 32) vv += t2;
        if (lane == 63) s.wsum[wv] = vv;
        __syncthreads();                 // wave sums visible
        u32 add = 0u;
        if (wv > 0) add += s.wsum[0];
        if (wv > 1) add += s.wsum[1];
        if (wv > 2) add += s.wsum[2];
        u32 cum = vv + add;
        if (tot != 0u && cum >= rem && cum - tot < rem) {  // unique boundary bin
            s.pref = pref | ((u32)tid << (bp * 8));
            s.rem = rem - (cum - tot);
        }
    }
    __syncthreads();
    u32 T = s.pref;        // K-th smallest km
    u32 need_eq = s.rem;   // how many km==T to take (lowest node index first)
    u32 run = 0u;          // high16 = #(km<T), low16 = #(km==T)
    for (int e = 0; e < per; ++e) {
        u32 km = km_of(scores[base + e]);
        if (km < T) run += 0x10000u;
        else if (km == T) run += 1u;
    }
    u32 v2 = run;
    u32 t3;
    t3 = __shfl(v2, lane - 1);  if (lane >= 1)  v2 += t3;
    t3 = __shfl(v2, lane - 2);  if (lane >= 2)  v2 += t3;
    t3 = __shfl(v2, lane - 4);  if (lane >= 4)  v2 += t3;
    t3 = __shfl(v2, lane - 8);  if (lane >= 8)  v2 += t3;
    t3 = __shfl(v2, lane - 16); if (lane >= 16) v2 += t3;
    t3 = __shfl(v2, lane - 32); if (lane >= 32) v2 += t3;
    if (lane == 63) s.wsum[wv] = v2;
    __syncthreads();
    u32 add2 = 0u;
    if (wv > 0) add2 += s.wsum[0];
    if (wv > 1) add2 += s.wsum[1];
    if (wv > 2) add2 += s.wsum[2];
    u32 cur = v2 + add2 - run;   // exclusive prefix for this thread's chunk
    for (int e = 0; e < per; ++e) {
        int v = base + e;
        u32 km = km_of(scores[v]);
        u32 ltb = cur >> 16;
        u32 eqb = cur & 0xFFFFu;
        u32 eqs = eqb < need_eq ? eqb : need_eq;
        int sel = 0;
        if (km < T) { sel = 1; cur += 0x10000u; }
        else if (km == T) { if (eqb < need_eq) sel = 1; cur += 1u; }
        if (sel) {
            int r = (int)(ltb + eqs);
            rank_l[v] = (u16)r;
            idx_l[r] = (u16)v;
            if (mirror) { grank[v] = r; gidx[r] = v; }
        } else {
            rank_l[v] = RNONE;
            if (mirror) grank[v] = -1;
        }
    }
    __syncthreads();   // LDS tables ready for same-block consumers
}

// SpMM (F=32) + relu; one wave per row, 8 lanes per neighbor, float4 per lane.
// EPI: fused in-register row@Wn (32x32) epilogue -> Zn[wid].
// FW4: fused row@Wn (32x2) epilogue -> ((float2*)Zn)[wid].
// SC : scores[wid] = relu_row @ svec.
// MASK: skip neighbors/self with mask_l[c]==0xFFFF (LDS u16 table).
template<bool REMAP, bool MASK, bool FW4, bool SC, bool EPI>
__device__ __forceinline__ void spmm_phase(
        const u16* __restrict__ ell, const int* __restrict__ rowcnt,
        const int* __restrict__ diag, const float* __restrict__ dnorm,
        const float* __restrict__ Z, const int* __restrict__ remap, const u16* mask_l,
        float* __restrict__ scores, const float* __restrict__ svec,
        const float* __restrict__ Wn, float* __restrict__ Zn,
        int n, int stride, int gwave, int nwaves, int lane)
{
    int g = lane >> 3;   // neighbor sub-slot 0..7
    int q = lane & 7;    // feature quad 0..7
    for (int wid = gwave; wid < n; wid += nwaves) {
        int cnt = rowcnt[wid];
        const u16* erow = ell + (size_t)wid * stride;
        float ax = 0.0f, ay = 0.0f, az = 0.0f, aw = 0.0f;
        for (int it = g; it < cnt; it += 8) {
            int c = erow[it];
            if (MASK && mask_l[c] == RNONE) continue;
            int zc = REMAP ? remap[c] : c;
            float dn = dnorm[c];
            const float4* zp = (const float4*)(Z + (size_t)zc * 32);
            float4 zv = zp[q];
            ax += dn * zv.x;
            ay += dn * zv.y;
            az += dn * zv.z;
            aw += dn * zv.w;
        }
        ax += __shfl_xor(ax, 8);  ay += __shfl_xor(ay, 8);
        az += __shfl_xor(az, 8);  aw += __shfl_xor(aw, 8);
        ax += __shfl_xor(ax, 16); ay += __shfl_xor(ay, 16);
        az += __shfl_xor(az, 16); aw += __shfl_xor(aw, 16);
        ax += __shfl_xor(ax, 32); ay += __shfl_xor(ay, 32);
        az += __shfl_xor(az, 32); aw += __shfl_xor(aw, 32);
        float ox = 0.0f, oy = 0.0f, oz = 0.0f, ow = 0.0f;
        if (g == 0) {   // lanes 0..7 hold the full sum for feature quad q
            float dr = dnorm[wid];
            bool selfok = !(MASK && mask_l[wid] == RNONE);
            if (selfok) {
                int zc = REMAP ? remap[wid] : wid;
                const float4* zp = (const float4*)(Z + (size_t)zc * 32);
                float4 zv = zp[q];
                float cf = (float)(diag[wid] + 1) * dr;
                ax += cf * zv.x;
                ay += cf * zv.y;
                az += cf * zv.z;
                aw += cf * zv.w;
            }
            ox = fmaxf(dr * ax, 0.0f);
            oy = fmaxf(dr * ay, 0.0f);
            oz = fmaxf(dr * az, 0.0f);
            ow = fmaxf(dr * aw, 0.0f);
            if (FW4) {
                int kb = q * 4;
                float p0 = ox * Wn[(kb + 0) * 2 + 0] + oy * Wn[(kb + 1) * 2 + 0]
                         + oz * Wn[(kb + 2) * 2 + 0] + ow * Wn[(kb + 3) * 2 + 0];
                float p1 = ox * Wn[(kb + 0) * 2 + 1] + oy * Wn[(kb + 1) * 2 + 1]
                         + oz * Wn[(kb + 2) * 2 + 1] + ow * Wn[(kb + 3) * 2 + 1];
                p0 += __shfl_xor(p0, 1);
                p1 += __shfl_xor(p1, 1);
                p0 += __shfl_xor(p0, 2);
                p1 += __shfl_xor(p1, 2);
                p0 += __shfl_xor(p0, 4);
                p1 += __shfl_xor(p1, 4);
                if (q == 0) {
                    float2 r;
                    r.x = p0;
                    r.y = p1;
                    ((float2*)Zn)[wid] = r;
                }
            } else if (SC) {
                const float4* sp = (const float4*)svec;
                float4 sv = sp[q];
                float pp = ox * sv.x + oy * sv.y + oz * sv.z + ow * sv.w;
                pp += __shfl_xor(pp, 1);
                pp += __shfl_xor(pp, 2);
                pp += __shfl_xor(pp, 4);
                if (q == 0) scores[wid] = pp;
            }
        }
        if (EPI) {
            // in-register row @ Wn (32x32): broadcast row[k] from lane k>>2
            int f = lane & 31;
            float acc = 0.0f;
#pragma unroll
            for (int k = 0; k < 32; ++k) {
                float comp = ((k & 3) == 0) ? ox : ((k & 3) == 1) ? oy
                           : ((k & 3) == 2) ? oz : ow;
                float rowk = __shfl(comp, k >> 2);
                acc += rowk * Wn[k * 32 + f];
            }
            if (lane < 32) Zn[(size_t)wid * 32 + f] = acc;
        }
    }
}

// Subgraph ELL for A1p = a[idx1][:,idx1]; rank/idx tables from block-local LDS.
__device__ __forceinline__ void subell_phase(const u16* __restrict__ ellA, const int* __restrict__ rowcntA,
        const int* __restrict__ diagA, const u16* idx_l, const u16* rank_l,
        u16* __restrict__ ellS, int* __restrict__ rowcntS, int* __restrict__ diagS, float* __restrict__ dnormS,
        int k1, int strideA, int strideS, int gwave, int nwaves, int lane)
{
    for (int wid = gwave; wid < k1; wid += nwaves) {
        int r = idx_l[wid];
        int cnt = rowcntA[r];
        const u16* erow = ellA + (size_t)r * strideA;
        u16* srow = ellS + (size_t)wid * strideS;
        int outn = 0;
        for (int t0 = 0; t0 < cnt; t0 += 64) {
            int it = t0 + lane;
            u16 rk = RNONE;
            if (it < cnt) rk = rank_l[erow[it]];
            unsigned long long b = __ballot(rk != RNONE);
            int ofs = __popcll(b & ((1ull << lane) - 1ull));
            if (rk != RNONE) srow[outn + ofs] = rk;
            outn += __popcll(b);
        }
        if (lane == 0) {
            int dg = diagA[r];
            rowcntS[wid] = outn;
            diagS[wid] = dg;
            dnormS[wid] = rsqrtf((float)(outn + dg + 1) + 1e-10f);
        }
    }
}

// Final SpMM (F=2) + 2-way softmax; unpool1 folded into the gat[] gather.
__device__ __forceinline__ void spmmout_phase(const u16* __restrict__ ell, const int* __restrict__ rowcnt,
        const int* __restrict__ diag, const float* __restrict__ dnorm, const float* __restrict__ Zr,
        const int* __restrict__ gat, float* __restrict__ out, int n, int stride,
        int gwave, int nwaves, int lane)
{
    const float2* Z2 = (const float2*)Zr;
    for (int wid = gwave; wid < n; wid += nwaves) {
        int cnt = rowcnt[wid];
        const u16* erow = ell + (size_t)wid * stride;
        float ax = 0.0f, ay = 0.0f;
        for (int it = lane; it < cnt; it += 64) {
            int c = erow[it];
            int rk = gat[c];
            if (rk >= 0) {
                float dn = dnorm[c];
                float2 zv = Z2[rk];
                ax += dn * zv.x;
                ay += dn * zv.y;
            }
        }
        ax += __shfl_xor(ax, 1);  ay += __shfl_xor(ay, 1);
        ax += __shfl_xor(ax, 2);  ay += __shfl_xor(ay, 2);
        ax += __shfl_xor(ax, 4);  ay += __shfl_xor(ay, 4);
        ax += __shfl_xor(ax, 8);  ay += __shfl_xor(ay, 8);
        ax += __shfl_xor(ax, 16); ay += __shfl_xor(ay, 16);
        ax += __shfl_xor(ax, 32); ay += __shfl_xor(ay, 32);
        if (lane == 0) {
            float dr = dnorm[wid];
            int rks = gat[wid];
            if (rks >= 0) {
                float cf = (float)(diag[wid] + 1) * dr;
                float2 zs = Z2[rks];
                ax += cf * zs.x;
                ay += cf * zs.y;
            }
            float v0 = dr * ax;
            float v1 = dr * ay;
            float m = fmaxf(v0, v1);
            float e0 = __expf(v0 - m);
            float e1 = __expf(v1 - m);
            float inv = 1.0f / (e0 + e1);
            float2 r;
            r.x = e0 * inv;
            r.y = e1 * inv;
            ((float2*)out)[wid] = r;
        }
    }
}

struct GcnP {
    const u16* ellA; const int* cntA; const int* diagA; const float* dnA;
    const float* Z1; float* sc1; int* rank1; int* idx1;
    u16* ellS; int* cntS; int* diagS; float* dnS;
    float* Z2f; float* sc2;
    float* Z3f; float* Z4r;
    const float* W2; const float* W3; const float* W4; const float* s1; const float* s2;
    float* out;
    u32* bar;
};

// ---------------------------------------------------------------------------
// Persistent pipeline (plain launch; custom barriers). 4 barriers:
//   A: spmm1+sc1+Z2f | B: local-topk1 + subell | C: spmm2+sc2+Z3f
//   D: local-topk2 + spmm3->Z4r | E: spmmout
// ---------------------------------------------------------------------------
__global__ __launch_bounds__(256, 4) void gcn_pipeline(GcnP p)
{
    __shared__ TkS sm;
    __shared__ u16 rank_l[NNODES];   // 16 KB
    __shared__ u16 idx_l[KP1];       // 8 KB
    int tid = threadIdx.x;
    int bid = blockIdx.x;
    int lane = tid & 63;
    int gwave = (bid * 256 + tid) >> 6;
    int nwaves = ((int)gridDim.x * 256) >> 6;
    int nblk = (int)gridDim.x;

    // A: GCN1 spmm + pool1 scores + fused Z2f = X1@W2 (all rows)
    spmm_phase<false, false, false, true, true>(p.ellA, p.cntA, p.diagA, p.dnA, p.Z1,
        (const int*)0, (const u16*)0, p.sc1, p.s1, p.W2, p.Z2f,
        NNODES, STRA, gwave, nwaves, lane);
    gbar(p.bar, bid, nblk);

    // B: every block computes topk1 into its own LDS (block 0 mirrors to
    //    global for phases C/E), then subgraph ELL using the LDS tables.
    topk_local(sm, rank_l, idx_l, p.sc1, NNODES, KP1, tid, p.rank1, p.idx1, bid == 0);
    subell_phase(p.ellA, p.cntA, p.diagA, idx_l, rank_l, p.ellS, p.cntS, p.diagS, p.dnS,
        KP1, STRA, STRS, gwave, nwaves, lane);
    gbar(p.bar, bid, nblk);

    // C: GCN2 on subgraph (Z gathered via global idx1) + fused Z3f = X2@W3
    spmm_phase<true, false, false, true, true>(p.ellS, p.cntS, p.diagS, p.dnS, p.Z2f,
        p.idx1, (const u16*)0, p.sc2, p.s2, p.W3, p.Z3f,
        KP1, STRS, gwave, nwaves, lane);
    gbar(p.bar, bid, nblk);

    // D: local topk2 (rank2 in LDS) + GCN3 with mask + fused W4 -> Z4r
    topk_local(sm, rank_l, idx_l, p.sc2, KP1, KP2, tid, (int*)0, (int*)0, false);
    spmm_phase<false, true, true, false, false>(p.ellS, p.cntS, p.diagS, p.dnS, p.Z3f,
        (const int*)0, rank_l, (float*)0, (const float*)0, p.W4, p.Z4r,
        KP1, STRS, gwave, nwaves, lane);
    gbar(p.bar, bid, nblk);

    // E: GCN4 + softmax (unpool1 folded into rank1 gather)
    spmmout_phase(p.ellA, p.cntA, p.diagA, p.dnA, p.Z4r, p.rank1, p.out,
        NNODES, STRA, gwave, nwaves, lane);
}

// ---------------------------------------------------------------------------
// Fallback path (no co-residency assumption): same phases as separate kernels.
// ---------------------------------------------------------------------------
__global__ __launch_bounds__(256) void k_spmmA(const u16* __restrict__ ell, const int* __restrict__ rowcnt,
        const int* __restrict__ diag, const float* __restrict__ dnorm, const float* __restrict__ Z,
        float* __restrict__ scores, const float* __restrict__ svec,
        const float* __restrict__ Wn, float* __restrict__ Zn, int n, int stride)
{
    int gwave = ((int)blockIdx.x * 256 + (int)threadIdx.x) >> 6;
    int nwaves = ((int)gridDim.x * 256) >> 6;
    spmm_phase<false, false, false, true, true>(ell, rowcnt, diag, dnorm, Z,
        (const int*)0, (const u16*)0, scores, svec, Wn, Zn, n, stride, gwave, nwaves, threadIdx.x & 63);
}

__global__ __launch_bounds__(256) void k_phaseB(const float* __restrict__ scores,
        int* __restrict__ grank, int* __restrict__ gidx,
        const u16* __restrict__ ellA, const int* __restrict__ rowcntA, const int* __restrict__ diagA,
        u16* __restrict__ ellS, int* __restrict__ rowcntS, int* __restrict__ diagS, float* __restrict__ dnormS)
{
    __shared__ TkS sm;
    __shared__ u16 rank_l[NNODES];
    __shared__ u16 idx_l[KP1];
    int gwave = ((int)blockIdx.x * 256 + (int)threadIdx.x) >> 6;
    int nwaves = ((int)gridDim.x * 256) >> 6;
    topk_local(sm, rank_l, idx_l, scores, NNODES, KP1, threadIdx.x, grank, gidx, blockIdx.x == 0);
    subell_phase(ellA, rowcntA, diagA, idx_l, rank_l, ellS, rowcntS, diagS, dnormS,
        KP1, STRA, STRS, gwave, nwaves, threadIdx.x & 63);
}

__global__ __launch_bounds__(256) void k_spmmC(const u16* __restrict__ ell, const int* __restrict__ rowcnt,
        const int* __restrict__ diag, const float* __restrict__ dnorm, const float* __restrict__ Z,
        const int* __restrict__ remap, float* __restrict__ scores, const float* __restrict__ svec,
        const float* __restrict__ Wn, float* __restrict__ Zn, int n, int stride)
{
    int gwave = ((int)blockIdx.x * 256 + (int)threadIdx.x) >> 6;
    int nwaves = ((int)gridDim.x * 256) >> 6;
    spmm_phase<true, false, false, true, true>(ell, rowcnt, diag, dnorm, Z,
        remap, (const u16*)0, scores, svec, Wn, Zn, n, stride, gwave, nwaves, threadIdx.x & 63);
}

__global__ __launch_bounds__(256) void k_phaseD(const float* __restrict__ scores,
        const u16* __restrict__ ell, const int* __restrict__ rowcnt,
        const int* __restrict__ diag, const float* __restrict__ dnorm, const float* __restrict__ Z,
        const float* __restrict__ Wn, float* __restrict__ Zn, int n, int stride)
{
    __shared__ TkS sm;
    __shared__ u16 rank_l[NNODES];
    __shared__ u16 idx_l[KP1];
    int gwave = ((int)blockIdx.x * 256 + (int)threadIdx.x) >> 6;
    int nwaves = ((int)gridDim.x * 256) >> 6;
    topk_local(sm, rank_l, idx_l, scores, KP1, KP2, threadIdx.x, (int*)0, (int*)0, false);
    spmm_phase<false, true, true, false, false>(ell, rowcnt, diag, dnorm, Z,
        (const int*)0, rank_l, (float*)0, (const float*)0, Wn, Zn, n, stride, gwave, nwaves, threadIdx.x & 63);
}

__global__ __launch_bounds__(256) void k_spmmout(const u16* __restrict__ ell, const int* __restrict__ rowcnt,
        const int* __restrict__ diag, const float* __restrict__ dnorm, const float* __restrict__ Zr,
        const int* __restrict__ gat, float* __restrict__ out, int n, int stride)
{
    int gwave = ((int)blockIdx.x * 256 + (int)threadIdx.x) >> 6;
    int nwaves = ((int)gridDim.x * 256) >> 6;
    spmmout_phase(ell, rowcnt, diag, dnorm, Zr, gat, out, n, stride, gwave, nwaves, threadIdx.x & 63);
}

#define CARVE(type, name, bytes) \
    type name = (type)wp; wp += (((size_t)(bytes)) + 255) & ~((size_t)255);

extern "C" void kernel_launch(void* const* d_in, const int* in_sizes, int n_in,
                              void* d_out, int out_size, void* d_ws, size_t ws_size,
                              hipStream_t stream)
{
    const float* x  = (const float*)d_in[0];
    const float* a  = (const float*)d_in[1];
    const float* W1 = (const float*)d_in[2];
    const float* W2 = (const float*)d_in[3];
    const float* W3 = (const float*)d_in[4];
    const float* W4 = (const float*)d_in[5];
    const float* s1 = (const float*)d_in[6];
    const float* s2 = (const float*)d_in[7];
    float* out = (float*)d_out;
    (void)in_sizes; (void)n_in; (void)out_size; (void)ws_size;

    char* wp = (char*)d_ws;
    CARVE(u16*,   ellA,  (size_t)NNODES * STRA * sizeof(u16));   // 5.2 MB
    CARVE(int*,   cntA,  NNODES * sizeof(int));
    CARVE(int*,   diagA, NNODES * sizeof(int));
    CARVE(float*, dnA,   NNODES * sizeof(float));
    CARVE(float*, Z1,    (size_t)NNODES * FH * sizeof(float));
    CARVE(float*, sc1,   NNODES * sizeof(float));
    CARVE(int*,   rank1, NNODES * sizeof(int));
    CARVE(int*,   idx1,  NNODES * sizeof(int));
    CARVE(u16*,   ellS,  (size_t)KP1 * STRS * sizeof(u16));      // 2.6 MB
    CARVE(int*,   cntS,  KP1 * sizeof(int));
    CARVE(int*,   diagS, KP1 * sizeof(int));
    CARVE(float*, dnS,   KP1 * sizeof(float));
    CARVE(float*, Z2f,   (size_t)NNODES * FH * sizeof(float));   // X1@W2 over ALL rows
    CARVE(float*, sc2,   KP1 * sizeof(float));
    CARVE(float*, Z3f,   (size_t)KP1 * FH * sizeof(float));      // X2@W3 over all pooled rows
    CARVE(float*, Z4r,   (size_t)KP1 * COUT * sizeof(float));    // rank-space X3@W4
    CARVE(u32*,   barws, BARWORDS * sizeof(u32));                // hierarchical barrier state

    // 1) one full 256MB pass -> ELL + co-launched Z1 = x@W1 + barrier init
    build_ell<<<NNODES + (NNODES * FH) / 256, 256, 0, stream>>>(
        a, NNODES, STRA, ellA, cntA, diagA, dnA, x, W1, Z1, FIN, barws);

    // 2) co-residency check for the persistent kernel (plain launch; the
    //    custom barrier deadlocks if all CGRID blocks can't be resident)
    static int g_ok = -1;
    if (g_ok < 0) {
        int maxb = 0;
        int ncu = 0;
        hipDeviceProp_t props;
        if (hipOccupancyMaxActiveBlocksPerMultiprocessor(&maxb, (const void*)gcn_pipeline, 256, 0)
                == hipSuccess
            && hipGetDeviceProperties(&props, 0) == hipSuccess)
            ncu = props.multiProcessorCount;
        g_ok = ((long)maxb * (long)ncu >= CGRID) ? 1 : 0;
    }

    if (g_ok) {
        GcnP pp;
        pp.ellA = ellA; pp.cntA = cntA; pp.diagA = diagA; pp.dnA = dnA;
        pp.Z1 = Z1; pp.sc1 = sc1; pp.rank1 = rank1; pp.idx1 = idx1;
        pp.ellS = ellS; pp.cntS = cntS; pp.diagS = diagS; pp.dnS = dnS;
        pp.Z2f = Z2f; pp.sc2 = sc2;
        pp.Z3f = Z3f; pp.Z4r = Z4r;
        pp.W2 = W2; pp.W3 = W3; pp.W4 = W4; pp.s1 = s1; pp.s2 = s2;
        pp.out = out;
        pp.bar = barws;
        gcn_pipeline<<<CGRID, 256, 0, stream>>>(pp);
    } else {
        k_spmmA<<<NNODES / 4, 256, 0, stream>>>(ellA, cntA, diagA, dnA, Z1,
            sc1, s1, W2, Z2f, NNODES, STRA);
        k_phaseB<<<KP1 / 4, 256, 0, stream>>>(sc1, rank1, idx1,
            ellA, cntA, diagA, ellS, cntS, diagS, dnS);
        k_spmmC<<<KP1 / 4, 256, 0, stream>>>(ellS, cntS, diagS, dnS, Z2f,
            idx1, sc2, s2, W3, Z3f, KP1, STRS);
        k_phaseD<<<KP1 / 4, 256, 0, stream>>>(sc2, ellS, cntS, diagS, dnS, Z3f,
            W4, Z4r, KP1, STRS);
        k_spmmout<<<NNODES / 4, 256, 0, stream>>>(ellA, cntA, diagA, dnA, Z4r, rank1, out, NNODES, STRA);
    }
}